// Round 8
// baseline (1334.721 us; speedup 1.0000x reference)
//
#include <hip/hip_runtime.h>

// ---------------------------------------------------------------------------
// EntropyCalculator: 2-layer post-norm transformer encoder + entropy head.
// B=256 S=512 D=128 H=4 HD=32 FF=512 V=256
// Register-transposed barrier-free oproj/FFN/entropy; 2-pass MFMA attention.
// ---------------------------------------------------------------------------

#define AS1 __attribute__((address_space(1)))
#define AS3 __attribute__((address_space(3)))

typedef __bf16 bf16x8 __attribute__((ext_vector_type(8)));
typedef float  f32x4  __attribute__((ext_vector_type(4)));

__device__ __forceinline__ unsigned short f2bf(float f) {
  union { float f; unsigned int u; } c; c.f = f;
  unsigned int u = c.u;
  u += 0x7FFFu + ((u >> 16) & 1u);   // round-to-nearest-even
  return (unsigned short)(u >> 16);
}
__device__ __forceinline__ float bf2f(unsigned short u) {
  union { unsigned int u; float f; } c; c.u = ((unsigned int)u) << 16;
  return c.f;
}

__device__ __forceinline__ float EXP2(float x) {
#if __has_builtin(__builtin_amdgcn_exp2f)
  return __builtin_amdgcn_exp2f(x);
#else
  return exp2f(x);
#endif
}

__device__ __forceinline__ void async_copy16(const void* g, void* l) {
  __builtin_amdgcn_global_load_lds((AS1 void*)(void*)g, (AS3 void*)l, 16, 0, 0);
}

__device__ __forceinline__ unsigned int cvtpk_bf16(float lo, float hi) {
  unsigned int r;
  asm("v_cvt_pk_bf16_f32 %0, %1, %2" : "=v"(r) : "v"(lo), "v"(hi));
  return r;
}
__device__ __forceinline__ void plswap32(unsigned int& a, unsigned int& b) {
  asm("v_permlane32_swap_b32 %0, %1" : "+v"(a), "+v"(b));
}
__device__ __forceinline__ void plswap16(unsigned int& a, unsigned int& b) {
  asm("v_permlane16_swap_b32 %0, %1" : "+v"(a), "+v"(b));
}

#define MFMA __builtin_amdgcn_mfma_f32_16x16x32_bf16

// ---------------------------------------------------------------------------
// weight conversions
// ---------------------------------------------------------------------------
// [N][K] f32 -> bf16 A-operand fragment lane order:
// frag (nb=row>>4, kb=k>>5) is 1KB contiguous; within frag, lane l=(g*16+c)
// holds row nb*16+c, k kb*32+g*8..+7 at halfword offset l*8.
__global__ void conv_permA(const float* __restrict__ src,
                           unsigned short* __restrict__ dst, int K, int n) {
  int i = blockIdx.x * 256 + threadIdx.x;
  if (i >= n) return;
  int row = i / K, k = i - row * K;
  int frag = (row >> 4) * (K >> 5) + (k >> 5);
  int d = frag * 512 + ((k >> 3) & 3) * 128 + (row & 15) * 8 + (k & 7);
  dst[d] = f2bf(src[i]);
}

// attn_w with Q rows pre-scaled by (1/sqrt(HD))*log2(e)
#define QSCALE 0.2550602989892646f
__global__ void conv_attn_w(const float* __restrict__ src,
                            unsigned short* __restrict__ dst) {
  int i = blockIdx.x * 256 + threadIdx.x;  // 98304
  int r = (i >> 7) % 384;
  float v = src[i];
  if (r < 128) v *= QSCALE;
  dst[i] = f2bf(v);
}
__global__ void conv_attn_b(const float* __restrict__ src,
                            float* __restrict__ dst) {
  int i = blockIdx.x * 256 + threadIdx.x;  // 768
  if (i < 768) {
    float v = src[i];
    if ((i % 384) < 128) v *= QSCALE;
    dst[i] = v;
  }
}

// ---------------------------------------------------------------------------
// Embedding + LayerNorm -> bf16 residual stream.  One wave per token.
// ---------------------------------------------------------------------------
__global__ __launch_bounds__(256) void embed_ln(
    const int* __restrict__ bytes, const float* __restrict__ emb,
    const float* __restrict__ pos, const float* __restrict__ g,
    const float* __restrict__ bta, unsigned short* __restrict__ hbf) {
  int wv = threadIdx.x >> 6, lane = threadIdx.x & 63;
  int tok = blockIdx.x * 4 + wv;
  int s = tok & 511;
  int bidx = bytes[tok];
  const float* e = emb + (size_t)bidx * 128;
  const float* p = pos + (size_t)s * 128;
  float x0 = e[lane] + p[lane];
  float x1 = e[lane + 64] + p[lane + 64];
  float sum = x0 + x1, ssq = x0 * x0 + x1 * x1;
#pragma unroll
  for (int off = 32; off; off >>= 1) {
    sum += __shfl_xor(sum, off);
    ssq += __shfl_xor(ssq, off);
  }
  float mean = sum * 0.0078125f;
  float var = ssq * 0.0078125f - mean * mean;
  float rs = rsqrtf(var + 1e-5f);
  float y0 = (x0 - mean) * rs * g[lane] + bta[lane];
  float y1 = (x1 - mean) * rs * g[lane + 64] + bta[lane + 64];
  size_t o = (size_t)tok * 128;
  hbf[o + lane] = f2bf(y0); hbf[o + lane + 64] = f2bf(y1);
}

// ---------------------------------------------------------------------------
// bf16 MFMA GEMM (QKV only):  C[M,N] = A[M,K] @ W[N,K]^T + bias, bf16 out.
// 128x128 tile, BK=64, 4 waves.
// ---------------------------------------------------------------------------
__global__ __launch_bounds__(256) void gemm_qkv(
    const unsigned short* __restrict__ A, const unsigned short* __restrict__ W,
    const float* __restrict__ bias, unsigned short* __restrict__ Cout,
    int M, int N, int K) {
  __shared__ __bf16 As[128 * 64];
  __shared__ __bf16 Ws[128 * 64];
  const int t = threadIdx.x;
  const int lane = t & 63, w = t >> 6;
  const int m0 = blockIdx.y * 128, n0 = blockIdx.x * 128;
  const int wm = (w >> 1) * 64, wn = (w & 1) * 64;
  f32x4 acc[4][4] = {};
  const int srow = w * 32 + (lane >> 3);
  const int scol = (lane & 7) * 8;

  for (int k0 = 0; k0 < K; k0 += 64) {
#pragma unroll
    for (int j = 0; j < 4; ++j) {
      int r = srow + j * 8;
      int ldsrow = w * 32 + j * 8;
      async_copy16(A + (size_t)(m0 + r) * K + k0 + scol, &As[ldsrow * 64]);
      async_copy16(W + (size_t)(n0 + r) * K + k0 + scol, &Ws[ldsrow * 64]);
    }
    __syncthreads();
#pragma unroll
    for (int kk = 0; kk < 2; ++kk) {
      bf16x8 af[4], bfr[4];
#pragma unroll
      for (int f = 0; f < 4; ++f) {
        af[f]  = *(const bf16x8*)&As[(wm + f * 16 + (lane & 15)) * 64 + kk * 32 + (lane >> 4) * 8];
        bfr[f] = *(const bf16x8*)&Ws[(wn + f * 16 + (lane & 15)) * 64 + kk * 32 + (lane >> 4) * 8];
      }
#pragma unroll
      for (int fi = 0; fi < 4; ++fi)
#pragma unroll
        for (int fj = 0; fj < 4; ++fj)
          acc[fi][fj] = MFMA(af[fi], bfr[fj], acc[fi][fj], 0, 0, 0);
    }
    __syncthreads();
  }

#pragma unroll
  for (int fj = 0; fj < 4; ++fj) {
    int col = n0 + wn + fj * 16 + (lane & 15);
    float bv = bias[col];
#pragma unroll
    for (int fi = 0; fi < 4; ++fi) {
#pragma unroll
      for (int r2 = 0; r2 < 4; ++r2) {
        int row = m0 + wm + fi * 16 + (lane >> 4) * 4 + r2;
        Cout[(size_t)row * N + col] = f2bf(acc[fi][fj][r2] + bv);
      }
    }
  }
}

// ---------------------------------------------------------------------------
// Fused out-proj + residual + LayerNorm, register-transposed, no LDS/barrier.
// ---------------------------------------------------------------------------
__global__ __launch_bounds__(256) void oproj_ln(
    const unsigned short* __restrict__ A, const unsigned short* __restrict__ Wp,
    const float* __restrict__ bias, unsigned short* __restrict__ h,
    const float* __restrict__ gamma, const float* __restrict__ beta) {
  const int lane = threadIdx.x & 63, w = threadIdx.x >> 6;
  const int c = lane & 15, g = lane >> 4;
  const size_t tok0 = (size_t)blockIdx.x * 128 + w * 32;

  bf16x8 at[2][4];
#pragma unroll
  for (int tf = 0; tf < 2; ++tf)
#pragma unroll
    for (int kk = 0; kk < 4; ++kk)
      at[tf][kk] =
          *(const bf16x8*)(A + (tok0 + tf * 16 + c) * 128 + kk * 32 + g * 8);

  f32x4 acc[8][2] = {};
#pragma unroll
  for (int db = 0; db < 8; ++db)
#pragma unroll
    for (int kk = 0; kk < 4; ++kk) {
      bf16x8 wf = *(const bf16x8*)(Wp + (db * 4 + kk) * 512 + lane * 8);
      acc[db][0] = MFMA(wf, at[0][kk], acc[db][0], 0, 0, 0);
      acc[db][1] = MFMA(wf, at[1][kk], acc[db][1], 0, 0, 0);
    }

#pragma unroll
  for (int tf = 0; tf < 2; ++tf) {
    unsigned short* hrow = h + (tok0 + tf * 16 + c) * 128;
    float x[8][4];
    float s_ = 0.f, q_ = 0.f;
#pragma unroll
    for (int db = 0; db < 8; ++db) {
      float4 bv = *(const float4*)(bias + db * 16 + g * 4);
      ushort4 rv = *(const ushort4*)(hrow + db * 16 + g * 4);
      x[db][0] = acc[db][tf][0] + bv.x + bf2f(rv.x);
      x[db][1] = acc[db][tf][1] + bv.y + bf2f(rv.y);
      x[db][2] = acc[db][tf][2] + bv.z + bf2f(rv.z);
      x[db][3] = acc[db][tf][3] + bv.w + bf2f(rv.w);
#pragma unroll
      for (int r = 0; r < 4; ++r) { s_ += x[db][r]; q_ += x[db][r] * x[db][r]; }
    }
    s_ += __shfl_xor(s_, 16); s_ += __shfl_xor(s_, 32);
    q_ += __shfl_xor(q_, 16); q_ += __shfl_xor(q_, 32);
    float mean = s_ * 0.0078125f;
    float var = q_ * 0.0078125f - mean * mean;
    float rs = rsqrtf(var + 1e-5f);
#pragma unroll
    for (int db = 0; db < 8; ++db) {
      float4 gv = *(const float4*)(gamma + db * 16 + g * 4);
      float4 bb = *(const float4*)(beta + db * 16 + g * 4);
      ushort4 o;
      o.x = f2bf((x[db][0] - mean) * rs * gv.x + bb.x);
      o.y = f2bf((x[db][1] - mean) * rs * gv.y + bb.y);
      o.z = f2bf((x[db][2] - mean) * rs * gv.z + bb.z);
      o.w = f2bf((x[db][3] - mean) * rs * gv.w + bb.w);
      *(ushort4*)(hrow + db * 16 + g * 4) = o;
    }
  }
}

// ---------------------------------------------------------------------------
// Fused FFN, register-transposed, G never leaves registers, no LDS/barriers.
// ---------------------------------------------------------------------------
__global__ __launch_bounds__(256) void ffn_reg(
    unsigned short* __restrict__ h, const unsigned short* __restrict__ W1p,
    const float* __restrict__ b1, const unsigned short* __restrict__ W2p,
    const float* __restrict__ b2, const float* __restrict__ gamma,
    const float* __restrict__ beta) {
  const int lane = threadIdx.x & 63, w = threadIdx.x >> 6;
  const int c = lane & 15, g = lane >> 4;
  const size_t tok0 = (size_t)blockIdx.x * 128 + w * 32;

  bf16x8 at[2][4];
#pragma unroll
  for (int tf = 0; tf < 2; ++tf)
#pragma unroll
    for (int kk = 0; kk < 4; ++kk)
      at[tf][kk] =
          *(const bf16x8*)(h + (tok0 + tf * 16 + c) * 128 + kk * 32 + g * 8);

  f32x4 acc[8][2] = {};
  for (int s = 0; s < 16; ++s) {          // 16 slices of 32 ff
    f32x4 d1[2][2] = {};                  // [ffhalf][tf]
#pragma unroll
    for (int kk = 0; kk < 4; ++kk) {
      bf16x8 wa = *(const bf16x8*)(W1p + ((2 * s) * 4 + kk) * 512 + lane * 8);
      bf16x8 wb = *(const bf16x8*)(W1p + ((2 * s + 1) * 4 + kk) * 512 + lane * 8);
      d1[0][0] = MFMA(wa, at[0][kk], d1[0][0], 0, 0, 0);
      d1[0][1] = MFMA(wa, at[1][kk], d1[0][1], 0, 0, 0);
      d1[1][0] = MFMA(wb, at[0][kk], d1[1][0], 0, 0, 0);
      d1[1][1] = MFMA(wb, at[1][kk], d1[1][1], 0, 0, 0);
    }
    float4 bva = *(const float4*)(b1 + s * 32 + g * 4);
    float4 bvb = *(const float4*)(b1 + s * 32 + 16 + g * 4);
    bf16x8 gp[2];
#pragma unroll
    for (int tf = 0; tf < 2; ++tf) {
      float pa0 = fmaxf(d1[0][tf][0] + bva.x, 0.f);
      float pa1 = fmaxf(d1[0][tf][1] + bva.y, 0.f);
      float pa2 = fmaxf(d1[0][tf][2] + bva.z, 0.f);
      float pa3 = fmaxf(d1[0][tf][3] + bva.w, 0.f);
      float pb0 = fmaxf(d1[1][tf][0] + bvb.x, 0.f);
      float pb1 = fmaxf(d1[1][tf][1] + bvb.y, 0.f);
      float pb2 = fmaxf(d1[1][tf][2] + bvb.z, 0.f);
      float pb3 = fmaxf(d1[1][tf][3] + bvb.w, 0.f);
      unsigned int w00 = cvtpk_bf16(pa0, pa1), w01 = cvtpk_bf16(pa2, pa3);
      unsigned int w10 = cvtpk_bf16(pb0, pb1), w11 = cvtpk_bf16(pb2, pb3);
      plswap32(w00, w10); plswap16(w00, w10);
      plswap32(w01, w11); plswap16(w01, w11);
      union { unsigned int u[4]; bf16x8 v; } pk;
      pk.u[0] = w00; pk.u[1] = w01; pk.u[2] = w10; pk.u[3] = w11;
      gp[tf] = pk.v;
    }
#pragma unroll
    for (int db = 0; db < 8; ++db) {
      bf16x8 w2 = *(const bf16x8*)(W2p + (db * 16 + s) * 512 + lane * 8);
      acc[db][0] = MFMA(w2, gp[0], acc[db][0], 0, 0, 0);
      acc[db][1] = MFMA(w2, gp[1], acc[db][1], 0, 0, 0);
    }
  }

#pragma unroll
  for (int tf = 0; tf < 2; ++tf) {
    unsigned short* hrow = h + (tok0 + tf * 16 + c) * 128;
    float x[8][4];
    float s_ = 0.f, q_ = 0.f;
#pragma unroll
    for (int db = 0; db < 8; ++db) {
      float4 bv = *(const float4*)(b2 + db * 16 + g * 4);
      ushort4 rv = *(const ushort4*)(hrow + db * 16 + g * 4);
      x[db][0] = acc[db][tf][0] + bv.x + bf2f(rv.x);
      x[db][1] = acc[db][tf][1] + bv.y + bf2f(rv.y);
      x[db][2] = acc[db][tf][2] + bv.z + bf2f(rv.z);
      x[db][3] = acc[db][tf][3] + bv.w + bf2f(rv.w);
#pragma unroll
      for (int r = 0; r < 4; ++r) { s_ += x[db][r]; q_ += x[db][r] * x[db][r]; }
    }
    s_ += __shfl_xor(s_, 16); s_ += __shfl_xor(s_, 32);
    q_ += __shfl_xor(q_, 16); q_ += __shfl_xor(q_, 32);
    float mean = s_ * 0.0078125f;
    float var = q_ * 0.0078125f - mean * mean;
    float rs = rsqrtf(var + 1e-5f);
#pragma unroll
    for (int db = 0; db < 8; ++db) {
      float4 gv = *(const float4*)(gamma + db * 16 + g * 4);
      float4 bb = *(const float4*)(beta + db * 16 + g * 4);
      ushort4 o;
      o.x = f2bf((x[db][0] - mean) * rs * gv.x + bb.x);
      o.y = f2bf((x[db][1] - mean) * rs * gv.y + bb.y);
      o.z = f2bf((x[db][2] - mean) * rs * gv.z + bb.z);
      o.w = f2bf((x[db][3] - mean) * rs * gv.w + bb.w);
      *(ushort4*)(hrow + db * 16 + g * 4) = o;
    }
  }
}

// ---------------------------------------------------------------------------
// Fused vocab projection + entropy, register-transposed, no LDS/barriers.
// ---------------------------------------------------------------------------
__global__ __launch_bounds__(256) void vocab_entropy(
    const unsigned short* __restrict__ h, const unsigned short* __restrict__ Wp,
    const float* __restrict__ bias, float* __restrict__ ent) {
  const int lane = threadIdx.x & 63, w = threadIdx.x >> 6;
  const int c = lane & 15, g = lane >> 4;
  const size_t tok0 = (size_t)blockIdx.x * 128 + w * 32;

  bf16x8 at[2][4];
#pragma unroll
  for (int tf = 0; tf < 2; ++tf)
#pragma unroll
    for (int kk = 0; kk < 4; ++kk)
      at[tf][kk] =
          *(const bf16x8*)(h + (tok0 + tf * 16 + c) * 128 + kk * 32 + g * 8);

  f32x4 acc[16][2] = {};
#pragma unroll
  for (int vb = 0; vb < 16; ++vb)
#pragma unroll
    for (int kk = 0; kk < 4; ++kk) {
      bf16x8 wf = *(const bf16x8*)(Wp + (vb * 4 + kk) * 512 + lane * 8);
      acc[vb][0] = MFMA(wf, at[0][kk], acc[vb][0], 0, 0, 0);
      acc[vb][1] = MFMA(wf, at[1][kk], acc[vb][1], 0, 0, 0);
    }

  const float L2E = 1.4426950408889634f;
#pragma unroll
  for (int tf = 0; tf < 2; ++tf) {
    float m_ = -1e30f;
#pragma unroll
    for (int vb = 0; vb < 16; ++vb) {
      float4 bv = *(const float4*)(bias + vb * 16 + g * 4);
      acc[vb][tf][0] += bv.x; acc[vb][tf][1] += bv.y;
      acc[vb][tf][2] += bv.z; acc[vb][tf][3] += bv.w;
      m_ = fmaxf(m_, fmaxf(fmaxf(acc[vb][tf][0], acc[vb][tf][1]),
                           fmaxf(acc[vb][tf][2], acc[vb][tf][3])));
    }
    m_ = fmaxf(m_, __shfl_xor(m_, 16));
    m_ = fmaxf(m_, __shfl_xor(m_, 32));
    float z_ = 0.f, sx_ = 0.f;
#pragma unroll
    for (int vb = 0; vb < 16; ++vb)
#pragma unroll
      for (int r = 0; r < 4; ++r) {
        float xx = acc[vb][tf][r];
        float e = EXP2((xx - m_) * L2E);
        z_ += e; sx_ += e * xx;
      }
    z_ += __shfl_xor(z_, 16);  z_ += __shfl_xor(z_, 32);
    sx_ += __shfl_xor(sx_, 16); sx_ += __shfl_xor(sx_, 32);
    if (g == 0) ent[tok0 + tf * 16 + c] = m_ + logf(z_) - sx_ / z_;
  }
}

// ---------------------------------------------------------------------------
// MFMA flash attention, register-resident P, 2-pass key sweep (37 KB LDS ->
// 4 blocks/CU).  Q pre-scaled by scale*log2e.  Block (512 thr) = (batch, head).
// Pass p stages keys p*256..p*256+255: threads <256 stage K rows, >=256 stage
// V^T.  l/ot accumulate across passes (no-max online softmax).
// ---------------------------------------------------------------------------
__global__ __launch_bounds__(512, 4) void attn_mfma(
    const unsigned short* __restrict__ qkv, unsigned short* __restrict__ obf) {
  __shared__ __bf16 Ks[256 * 40];   // 20480 B, stride 40 hw (16B-aligned rows)
  __shared__ __bf16 Vt[32 * 264];   // 16896 B, stride 264 hw (16B-aligned)

  const int hh = blockIdx.x & 3, bl = blockIdx.x >> 2;
  const int t = threadIdx.x;
  const int lane = t & 63, wv = t >> 6;
  const int c = lane & 15, g = lane >> 4;
  const size_t tok0 = (size_t)bl * 512;

  // Q fragments (B-operand): lane holds Q[qf*16+c][g*8 .. g*8+7]
  bf16x8 qb[4];
  {
    const unsigned short* qp = qkv + (tok0 + wv * 64) * 384 + hh * 32;
#pragma unroll
    for (int qf = 0; qf < 4; ++qf)
      qb[qf] = *(const bf16x8*)(qp + (size_t)(qf * 16 + c) * 384 + g * 8);
  }

  f32x4 ot[4][2] = {};
  float l[4] = {0.f, 0.f, 0.f, 0.f};
  const f32x4 zz = {0.f, 0.f, 0.f, 0.f};

  for (int p = 0; p < 2; ++p) {
    if (p) __syncthreads();   // prior pass's reads done before overwrite
    {
      int key = t & 255;
      const unsigned short* kr =
          qkv + (tok0 + p * 256 + key) * 384 + 128 + hh * 32;
      if (t < 256) {
        bf16x8 k0 = *(const bf16x8*)(kr);
        bf16x8 k1 = *(const bf16x8*)(kr + 8);
        bf16x8 k2 = *(const bf16x8*)(kr + 16);
        bf16x8 k3 = *(const bf16x8*)(kr + 24);
        __bf16* kd = Ks + key * 40;
        *(bf16x8*)(kd + 0) = k0;  *(bf16x8*)(kd + 8) = k1;
        *(bf16x8*)(kd + 16) = k2; *(bf16x8*)(kd + 24) = k3;
      } else {
        const unsigned short* vr = kr + 128;
        bf16x8 v0 = *(const bf16x8*)(vr);
        bf16x8 v1 = *(const bf16x8*)(vr + 8);
        bf16x8 v2 = *(const bf16x8*)(vr + 16);
        bf16x8 v3 = *(const bf16x8*)(vr + 24);
#pragma unroll
        for (int i = 0; i < 8; ++i) {
          Vt[(i)      * 264 + key] = v0[i];
          Vt[(i + 8)  * 264 + key] = v1[i];
          Vt[(i + 16) * 264 + key] = v2[i];
          Vt[(i + 24) * 264 + key] = v3[i];
        }
      }
    }
    __syncthreads();

    for (int kt = 0; kt < 4; ++kt) {
      bf16x8 ka[4];
#pragma unroll
      for (int kf = 0; kf < 4; ++kf)
        ka[kf] = *(const bf16x8*)&Ks[(kt * 64 + kf * 16 + c) * 40 + g * 8];
      bf16x8 vb[2][2];
#pragma unroll
      for (int hf = 0; hf < 2; ++hf)
#pragma unroll
        for (int ksl = 0; ksl < 2; ++ksl)
          vb[hf][ksl] = *(const bf16x8*)&Vt[(hf * 16 + c) * 264 + kt * 64 +
                                            ksl * 32 + g * 8];

#pragma unroll
      for (int qf = 0; qf < 4; ++qf) {
        f32x4 sA = MFMA(ka[0], qb[qf], zz, 0, 0, 0);
        f32x4 sB = MFMA(ka[1], qb[qf], zz, 0, 0, 0);
        f32x4 sC = MFMA(ka[2], qb[qf], zz, 0, 0, 0);
        f32x4 sD = MFMA(ka[3], qb[qf], zz, 0, 0, 0);

        {
          float pa0 = EXP2(sA[0]), pa1 = EXP2(sA[1]);
          float pa2 = EXP2(sA[2]), pa3 = EXP2(sA[3]);
          float pb0 = EXP2(sB[0]), pb1 = EXP2(sB[1]);
          float pb2 = EXP2(sB[2]), pb3 = EXP2(sB[3]);
          l[qf] += ((pa0 + pa1) + (pa2 + pa3)) + ((pb0 + pb1) + (pb2 + pb3));
          unsigned int w00 = cvtpk_bf16(pa0, pa1), w01 = cvtpk_bf16(pa2, pa3);
          unsigned int w10 = cvtpk_bf16(pb0, pb1), w11 = cvtpk_bf16(pb2, pb3);
          plswap32(w00, w10); plswap16(w00, w10);
          plswap32(w01, w11); plswap16(w01, w11);
          union { unsigned int u[4]; bf16x8 v; } pk;
          pk.u[0] = w00; pk.u[1] = w01; pk.u[2] = w10; pk.u[3] = w11;
          ot[qf][0] = MFMA(vb[0][0], pk.v, ot[qf][0], 0, 0, 0);
          ot[qf][1] = MFMA(vb[1][0], pk.v, ot[qf][1], 0, 0, 0);
        }
        {
          float pa0 = EXP2(sC[0]), pa1 = EXP2(sC[1]);
          float pa2 = EXP2(sC[2]), pa3 = EXP2(sC[3]);
          float pb0 = EXP2(sD[0]), pb1 = EXP2(sD[1]);
          float pb2 = EXP2(sD[2]), pb3 = EXP2(sD[3]);
          l[qf] += ((pa0 + pa1) + (pa2 + pa3)) + ((pb0 + pb1) + (pb2 + pb3));
          unsigned int w00 = cvtpk_bf16(pa0, pa1), w01 = cvtpk_bf16(pa2, pa3);
          unsigned int w10 = cvtpk_bf16(pb0, pb1), w11 = cvtpk_bf16(pb2, pb3);
          plswap32(w00, w10); plswap16(w00, w10);
          plswap32(w01, w11); plswap16(w01, w11);
          union { unsigned int u[4]; bf16x8 v; } pk;
          pk.u[0] = w00; pk.u[1] = w01; pk.u[2] = w10; pk.u[3] = w11;
          ot[qf][0] = MFMA(vb[0][1], pk.v, ot[qf][0], 0, 0, 0);
          ot[qf][1] = MFMA(vb[1][1], pk.v, ot[qf][1], 0, 0, 0);
        }
      }
    }
  }

#pragma unroll
  for (int qf = 0; qf < 4; ++qf) {
    l[qf] += __shfl_xor(l[qf], 16);
    l[qf] += __shfl_xor(l[qf], 32);
  }
#pragma unroll
  for (int qf = 0; qf < 4; ++qf) {
    float rl = 1.0f / l[qf];
#pragma unroll
    for (int hf = 0; hf < 2; ++hf) {
      ushort4 pk;
      pk.x = f2bf(ot[qf][hf][0] * rl);
      pk.y = f2bf(ot[qf][hf][1] * rl);
      pk.z = f2bf(ot[qf][hf][2] * rl);
      pk.w = f2bf(ot[qf][hf][3] * rl);
      *(ushort4*)(obf + (tok0 + wv * 64 + qf * 16 + c) * 128 + hh * 32 +
                  hf * 16 + g * 4) = pk;
    }
  }
}

// ---------------------------------------------------------------------------
__global__ __launch_bounds__(64) void avg_entropy_kernel(
    const float* __restrict__ ent, float* __restrict__ out) {
  int s = blockIdx.x, lane = threadIdx.x;
  float a = 0.f;
  for (int b = lane; b < 256; b += 64) a += ent[(size_t)b * 512 + s];
#pragma unroll
  for (int off = 32; off; off >>= 1) a += __shfl_xor(a, off);
  if (lane == 0) out[s] = a * 0.00390625f;
}

__global__ __launch_bounds__(512) void seg_kernel(float* out) {
  __shared__ int cs[512];
  int i = threadIdx.x;
  float e = out[i];
  cs[i] = (i >= 1 && e > 4.0f) ? 1 : 0;
  __syncthreads();
  for (int off = 1; off < 512; off <<= 1) {
    int v = (i >= off) ? cs[i - off] : 0;
    __syncthreads();
    cs[i] += v;
    __syncthreads();
  }
  out[512 + i] = (float)cs[i];
}

// ---------------------------------------------------------------------------
extern "C" void kernel_launch(void* const* d_in, const int* in_sizes, int n_in,
                              void* d_out, int out_size, void* d_ws,
                              size_t ws_size, hipStream_t stream) {
  (void)in_sizes; (void)n_in; (void)out_size; (void)ws_size;
  const int*   input_bytes = (const int*)d_in[0];
  const float* emb    = (const float*)d_in[1];
  const float* pos    = (const float*)d_in[2];
  const float* ln_g   = (const float*)d_in[3];
  const float* ln_b   = (const float*)d_in[4];
  const float* attn_w = (const float*)d_in[5];
  const float* attn_b = (const float*)d_in[6];
  const float* out_w  = (const float*)d_in[7];
  const float* out_b  = (const float*)d_in[8];
  const float* ff1_w  = (const float*)d_in[9];
  const float* ff1_b  = (const float*)d_in[10];
  const float* ff2_w  = (const float*)d_in[11];
  const float* ff2_b  = (const float*)d_in[12];
  const float* n1_g   = (const float*)d_in[13];
  const float* n1_b   = (const float*)d_in[14];
  const float* n2_g   = (const float*)d_in[15];
  const float* n2_b   = (const float*)d_in[16];
  const float* proj_w = (const float*)d_in[17];
  const float* proj_b = (const float*)d_in[18];

  char* ws = (char*)d_ws;
  unsigned short* hbf  = (unsigned short*)(ws);                // 32 MB
  unsigned short* obf  = (unsigned short*)(ws + 33554432);     // 32 MB
  unsigned short* qkvc = (unsigned short*)(ws + 67108864);     // 96 MB
  unsigned short* wbf  = (unsigned short*)(ws + 167772160);    // ~0.85 MB
  float*          absb = (float*)(ws + 168624128);             // 3 KB
  float*          entb = (float*)(ws + 168628224);             // 0.5 MB

  unsigned short* attnw_bf = wbf;
  unsigned short* outwA    = wbf + 98304;
  unsigned short* w1A      = wbf + 131072;
  unsigned short* w2A      = wbf + 262144;
  unsigned short* projA    = wbf + 393216;

  conv_attn_w<<<384, 256, 0, stream>>>(attn_w, attnw_bf);
  conv_attn_b<<<3, 256, 0, stream>>>(attn_b, absb);
  for (int l = 0; l < 2; ++l) {
    conv_permA<<<64, 256, 0, stream>>>(out_w + l * 16384, outwA + l * 16384,
                                       128, 16384);
    conv_permA<<<256, 256, 0, stream>>>(ff1_w + l * 65536, w1A + l * 65536,
                                        128, 65536);
    conv_permA<<<256, 256, 0, stream>>>(ff2_w + l * 65536, w2A + l * 65536,
                                        512, 65536);
  }
  conv_permA<<<128, 256, 0, stream>>>(proj_w, projA, 128, 32768);

  embed_ln<<<32768, 256, 0, stream>>>(input_bytes, emb, pos, ln_g, ln_b, hbf);

  for (int l = 0; l < 2; ++l) {
    gemm_qkv<<<dim3(3, 1024), 256, 0, stream>>>(
        hbf, attnw_bf + l * 49152, absb + l * 384, qkvc, 131072, 384, 128);
    attn_mfma<<<1024, 512, 0, stream>>>(qkvc, obf);
    oproj_ln<<<1024, 256, 0, stream>>>(obf, outwA + l * 16384, out_b + l * 128,
                                       hbf, n1_g + l * 128, n1_b + l * 128);
    ffn_reg<<<1024, 256, 0, stream>>>(hbf, w1A + l * 65536, ff1_b + l * 512,
                                      w2A + l * 65536, ff2_b + l * 128,
                                      n2_g + l * 128, n2_b + l * 128);
  }

  vocab_entropy<<<1024, 256, 0, stream>>>(hbf, projA, proj_b, entb);
  avg_entropy_kernel<<<512, 64, 0, stream>>>(entb, (float*)d_out);
  seg_kernel<<<1, 512, 0, stream>>>((float*)d_out);
}

// Round 9
// 571.636 us; speedup vs baseline: 2.3349x; 2.3349x over previous
//
#include <hip/hip_runtime.h>

// ---------------------------------------------------------------------------
// EntropyCalculator: 2-layer post-norm transformer encoder + entropy head.
// B=256 S=512 D=128 H=4 HD=32 FF=512 V=256
// Register-transposed barrier-free qkv/oproj/FFN/entropy; MFMA flash attn.
// ---------------------------------------------------------------------------

#define AS1 __attribute__((address_space(1)))
#define AS3 __attribute__((address_space(3)))

typedef __bf16 bf16x8 __attribute__((ext_vector_type(8)));
typedef float  f32x4  __attribute__((ext_vector_type(4)));

__device__ __forceinline__ unsigned short f2bf(float f) {
  union { float f; unsigned int u; } c; c.f = f;
  unsigned int u = c.u;
  u += 0x7FFFu + ((u >> 16) & 1u);   // round-to-nearest-even
  return (unsigned short)(u >> 16);
}
__device__ __forceinline__ float bf2f(unsigned short u) {
  union { unsigned int u; float f; } c; c.u = ((unsigned int)u) << 16;
  return c.f;
}

__device__ __forceinline__ float EXP2(float x) {
#if __has_builtin(__builtin_amdgcn_exp2f)
  return __builtin_amdgcn_exp2f(x);
#else
  return exp2f(x);
#endif
}

__device__ __forceinline__ unsigned int cvtpk_bf16(float lo, float hi) {
  unsigned int r;
  asm("v_cvt_pk_bf16_f32 %0, %1, %2" : "=v"(r) : "v"(lo), "v"(hi));
  return r;
}
__device__ __forceinline__ void plswap32(unsigned int& a, unsigned int& b) {
  asm("v_permlane32_swap_b32 %0, %1" : "+v"(a), "+v"(b));
}
__device__ __forceinline__ void plswap16(unsigned int& a, unsigned int& b) {
  asm("v_permlane16_swap_b32 %0, %1" : "+v"(a), "+v"(b));
}

#define MFMA __builtin_amdgcn_mfma_f32_16x16x32_bf16

// ---------------------------------------------------------------------------
// weight conversions
// ---------------------------------------------------------------------------
// [N][K] f32 -> bf16 A-operand fragment lane order:
// frag (nb=row>>4, kb=k>>5) is 1KB contiguous; within frag, lane l=(g*16+c)
// holds row nb*16+c, k kb*32+g*8..+7 at halfword offset l*8.
__global__ void conv_permA(const float* __restrict__ src,
                           unsigned short* __restrict__ dst, int K, int n) {
  int i = blockIdx.x * 256 + threadIdx.x;
  if (i >= n) return;
  int row = i / K, k = i - row * K;
  int frag = (row >> 4) * (K >> 5) + (k >> 5);
  int d = frag * 512 + ((k >> 3) & 3) * 128 + (row & 15) * 8 + (k & 7);
  dst[d] = f2bf(src[i]);
}

// attn_w [2][384][128] -> per-layer A-frag order, Q rows scaled by QSCALE.
#define QSCALE 0.2550602989892646f
__global__ void conv_attn_wA(const float* __restrict__ src,
                             unsigned short* __restrict__ dst) {
  int i = blockIdx.x * 256 + threadIdx.x;  // 98304
  int l = i / 49152, rem = i - l * 49152;
  int row = rem >> 7, k = rem & 127;
  float v = src[i];
  if (row < 128) v *= QSCALE;
  int frag = (row >> 4) * 4 + (k >> 5);
  int d = frag * 512 + ((k >> 3) & 3) * 128 + (row & 15) * 8 + (k & 7);
  dst[l * 49152 + d] = f2bf(v);
}
__global__ void conv_attn_b(const float* __restrict__ src,
                            float* __restrict__ dst) {
  int i = blockIdx.x * 256 + threadIdx.x;  // 768
  if (i < 768) {
    float v = src[i];
    if ((i % 384) < 128) v *= QSCALE;
    dst[i] = v;
  }
}

// ---------------------------------------------------------------------------
// Embedding + LayerNorm -> bf16 residual stream.  One wave per token.
// ---------------------------------------------------------------------------
__global__ __launch_bounds__(256) void embed_ln(
    const int* __restrict__ bytes, const float* __restrict__ emb,
    const float* __restrict__ pos, const float* __restrict__ g,
    const float* __restrict__ bta, unsigned short* __restrict__ hbf) {
  int wv = threadIdx.x >> 6, lane = threadIdx.x & 63;
  int tok = blockIdx.x * 4 + wv;
  int s = tok & 511;
  int bidx = bytes[tok];
  const float* e = emb + (size_t)bidx * 128;
  const float* p = pos + (size_t)s * 128;
  float x0 = e[lane] + p[lane];
  float x1 = e[lane + 64] + p[lane + 64];
  float sum = x0 + x1, ssq = x0 * x0 + x1 * x1;
#pragma unroll
  for (int off = 32; off; off >>= 1) {
    sum += __shfl_xor(sum, off);
    ssq += __shfl_xor(ssq, off);
  }
  float mean = sum * 0.0078125f;
  float var = ssq * 0.0078125f - mean * mean;
  float rs = rsqrtf(var + 1e-5f);
  float y0 = (x0 - mean) * rs * g[lane] + bta[lane];
  float y1 = (x1 - mean) * rs * g[lane + 64] + bta[lane + 64];
  size_t o = (size_t)tok * 128;
  hbf[o + lane] = f2bf(y0); hbf[o + lane + 64] = f2bf(y1);
}

// ---------------------------------------------------------------------------
// Register-transposed QKV projection, no LDS/barriers.
// 256 thr = 4 waves; wave owns 32 tokens.  q/k/v as 3 sequential N=128 segs.
// Writes [token][384] bf16 (Q pre-scaled via weights/bias).
// ---------------------------------------------------------------------------
__global__ __launch_bounds__(256) void qkv_reg(
    const unsigned short* __restrict__ h, const unsigned short* __restrict__ Wp,
    const float* __restrict__ bias, unsigned short* __restrict__ qkv) {
  const int lane = threadIdx.x & 63, w = threadIdx.x >> 6;
  const int c = lane & 15, g = lane >> 4;
  const size_t tok0 = (size_t)blockIdx.x * 128 + w * 32;

  bf16x8 at[2][4];
#pragma unroll
  for (int tf = 0; tf < 2; ++tf)
#pragma unroll
    for (int kk = 0; kk < 4; ++kk)
      at[tf][kk] =
          *(const bf16x8*)(h + (tok0 + tf * 16 + c) * 128 + kk * 32 + g * 8);

  for (int seg = 0; seg < 3; ++seg) {
    f32x4 acc[8][2] = {};
#pragma unroll
    for (int db = 0; db < 8; ++db)
#pragma unroll
      for (int kk = 0; kk < 4; ++kk) {
        bf16x8 wf =
            *(const bf16x8*)(Wp + ((seg * 8 + db) * 4 + kk) * 512 + lane * 8);
        acc[db][0] = MFMA(wf, at[0][kk], acc[db][0], 0, 0, 0);
        acc[db][1] = MFMA(wf, at[1][kk], acc[db][1], 0, 0, 0);
      }
#pragma unroll
    for (int tf = 0; tf < 2; ++tf) {
      unsigned short* orow = qkv + (tok0 + tf * 16 + c) * 384 + seg * 128;
#pragma unroll
      for (int db = 0; db < 8; ++db) {
        float4 bv = *(const float4*)(bias + seg * 128 + db * 16 + g * 4);
        ushort4 o;
        o.x = f2bf(acc[db][tf][0] + bv.x);
        o.y = f2bf(acc[db][tf][1] + bv.y);
        o.z = f2bf(acc[db][tf][2] + bv.z);
        o.w = f2bf(acc[db][tf][3] + bv.w);
        *(ushort4*)(orow + db * 16 + g * 4) = o;
      }
    }
  }
}

// ---------------------------------------------------------------------------
// Fused out-proj + residual + LayerNorm, register-transposed, no LDS/barrier.
// ---------------------------------------------------------------------------
__global__ __launch_bounds__(256) void oproj_ln(
    const unsigned short* __restrict__ A, const unsigned short* __restrict__ Wp,
    const float* __restrict__ bias, unsigned short* __restrict__ h,
    const float* __restrict__ gamma, const float* __restrict__ beta) {
  const int lane = threadIdx.x & 63, w = threadIdx.x >> 6;
  const int c = lane & 15, g = lane >> 4;
  const size_t tok0 = (size_t)blockIdx.x * 128 + w * 32;

  bf16x8 at[2][4];
#pragma unroll
  for (int tf = 0; tf < 2; ++tf)
#pragma unroll
    for (int kk = 0; kk < 4; ++kk)
      at[tf][kk] =
          *(const bf16x8*)(A + (tok0 + tf * 16 + c) * 128 + kk * 32 + g * 8);

  f32x4 acc[8][2] = {};
#pragma unroll
  for (int db = 0; db < 8; ++db)
#pragma unroll
    for (int kk = 0; kk < 4; ++kk) {
      bf16x8 wf = *(const bf16x8*)(Wp + (db * 4 + kk) * 512 + lane * 8);
      acc[db][0] = MFMA(wf, at[0][kk], acc[db][0], 0, 0, 0);
      acc[db][1] = MFMA(wf, at[1][kk], acc[db][1], 0, 0, 0);
    }

#pragma unroll
  for (int tf = 0; tf < 2; ++tf) {
    unsigned short* hrow = h + (tok0 + tf * 16 + c) * 128;
    float x[8][4];
    float s_ = 0.f, q_ = 0.f;
#pragma unroll
    for (int db = 0; db < 8; ++db) {
      float4 bv = *(const float4*)(bias + db * 16 + g * 4);
      ushort4 rv = *(const ushort4*)(hrow + db * 16 + g * 4);
      x[db][0] = acc[db][tf][0] + bv.x + bf2f(rv.x);
      x[db][1] = acc[db][tf][1] + bv.y + bf2f(rv.y);
      x[db][2] = acc[db][tf][2] + bv.z + bf2f(rv.z);
      x[db][3] = acc[db][tf][3] + bv.w + bf2f(rv.w);
#pragma unroll
      for (int r = 0; r < 4; ++r) { s_ += x[db][r]; q_ += x[db][r] * x[db][r]; }
    }
    s_ += __shfl_xor(s_, 16); s_ += __shfl_xor(s_, 32);
    q_ += __shfl_xor(q_, 16); q_ += __shfl_xor(q_, 32);
    float mean = s_ * 0.0078125f;
    float var = q_ * 0.0078125f - mean * mean;
    float rs = rsqrtf(var + 1e-5f);
#pragma unroll
    for (int db = 0; db < 8; ++db) {
      float4 gv = *(const float4*)(gamma + db * 16 + g * 4);
      float4 bb = *(const float4*)(beta + db * 16 + g * 4);
      ushort4 o;
      o.x = f2bf((x[db][0] - mean) * rs * gv.x + bb.x);
      o.y = f2bf((x[db][1] - mean) * rs * gv.y + bb.y);
      o.z = f2bf((x[db][2] - mean) * rs * gv.z + bb.z);
      o.w = f2bf((x[db][3] - mean) * rs * gv.w + bb.w);
      *(ushort4*)(hrow + db * 16 + g * 4) = o;
    }
  }
}

// ---------------------------------------------------------------------------
// Fused FFN, register-transposed, G never leaves registers, no LDS/barriers.
// ---------------------------------------------------------------------------
__global__ __launch_bounds__(256) void ffn_reg(
    unsigned short* __restrict__ h, const unsigned short* __restrict__ W1p,
    const float* __restrict__ b1, const unsigned short* __restrict__ W2p,
    const float* __restrict__ b2, const float* __restrict__ gamma,
    const float* __restrict__ beta) {
  const int lane = threadIdx.x & 63, w = threadIdx.x >> 6;
  const int c = lane & 15, g = lane >> 4;
  const size_t tok0 = (size_t)blockIdx.x * 128 + w * 32;

  bf16x8 at[2][4];
#pragma unroll
  for (int tf = 0; tf < 2; ++tf)
#pragma unroll
    for (int kk = 0; kk < 4; ++kk)
      at[tf][kk] =
          *(const bf16x8*)(h + (tok0 + tf * 16 + c) * 128 + kk * 32 + g * 8);

  f32x4 acc[8][2] = {};
  for (int s = 0; s < 16; ++s) {          // 16 slices of 32 ff
    f32x4 d1[2][2] = {};                  // [ffhalf][tf]
#pragma unroll
    for (int kk = 0; kk < 4; ++kk) {
      bf16x8 wa = *(const bf16x8*)(W1p + ((2 * s) * 4 + kk) * 512 + lane * 8);
      bf16x8 wb = *(const bf16x8*)(W1p + ((2 * s + 1) * 4 + kk) * 512 + lane * 8);
      d1[0][0] = MFMA(wa, at[0][kk], d1[0][0], 0, 0, 0);
      d1[0][1] = MFMA(wa, at[1][kk], d1[0][1], 0, 0, 0);
      d1[1][0] = MFMA(wb, at[0][kk], d1[1][0], 0, 0, 0);
      d1[1][1] = MFMA(wb, at[1][kk], d1[1][1], 0, 0, 0);
    }
    float4 bva = *(const float4*)(b1 + s * 32 + g * 4);
    float4 bvb = *(const float4*)(b1 + s * 32 + 16 + g * 4);
    bf16x8 gp[2];
#pragma unroll
    for (int tf = 0; tf < 2; ++tf) {
      float pa0 = fmaxf(d1[0][tf][0] + bva.x, 0.f);
      float pa1 = fmaxf(d1[0][tf][1] + bva.y, 0.f);
      float pa2 = fmaxf(d1[0][tf][2] + bva.z, 0.f);
      float pa3 = fmaxf(d1[0][tf][3] + bva.w, 0.f);
      float pb0 = fmaxf(d1[1][tf][0] + bvb.x, 0.f);
      float pb1 = fmaxf(d1[1][tf][1] + bvb.y, 0.f);
      float pb2 = fmaxf(d1[1][tf][2] + bvb.z, 0.f);
      float pb3 = fmaxf(d1[1][tf][3] + bvb.w, 0.f);
      unsigned int w00 = cvtpk_bf16(pa0, pa1), w01 = cvtpk_bf16(pa2, pa3);
      unsigned int w10 = cvtpk_bf16(pb0, pb1), w11 = cvtpk_bf16(pb2, pb3);
      plswap32(w00, w10); plswap16(w00, w10);
      plswap32(w01, w11); plswap16(w01, w11);
      union { unsigned int u[4]; bf16x8 v; } pk;
      pk.u[0] = w00; pk.u[1] = w01; pk.u[2] = w10; pk.u[3] = w11;
      gp[tf] = pk.v;
    }
#pragma unroll
    for (int db = 0; db < 8; ++db) {
      bf16x8 w2 = *(const bf16x8*)(W2p + (db * 16 + s) * 512 + lane * 8);
      acc[db][0] = MFMA(w2, gp[0], acc[db][0], 0, 0, 0);
      acc[db][1] = MFMA(w2, gp[1], acc[db][1], 0, 0, 0);
    }
  }

#pragma unroll
  for (int tf = 0; tf < 2; ++tf) {
    unsigned short* hrow = h + (tok0 + tf * 16 + c) * 128;
    float x[8][4];
    float s_ = 0.f, q_ = 0.f;
#pragma unroll
    for (int db = 0; db < 8; ++db) {
      float4 bv = *(const float4*)(b2 + db * 16 + g * 4);
      ushort4 rv = *(const ushort4*)(hrow + db * 16 + g * 4);
      x[db][0] = acc[db][tf][0] + bv.x + bf2f(rv.x);
      x[db][1] = acc[db][tf][1] + bv.y + bf2f(rv.y);
      x[db][2] = acc[db][tf][2] + bv.z + bf2f(rv.z);
      x[db][3] = acc[db][tf][3] + bv.w + bf2f(rv.w);
#pragma unroll
      for (int r = 0; r < 4; ++r) { s_ += x[db][r]; q_ += x[db][r] * x[db][r]; }
    }
    s_ += __shfl_xor(s_, 16); s_ += __shfl_xor(s_, 32);
    q_ += __shfl_xor(q_, 16); q_ += __shfl_xor(q_, 32);
    float mean = s_ * 0.0078125f;
    float var = q_ * 0.0078125f - mean * mean;
    float rs = rsqrtf(var + 1e-5f);
#pragma unroll
    for (int db = 0; db < 8; ++db) {
      float4 gv = *(const float4*)(gamma + db * 16 + g * 4);
      float4 bb = *(const float4*)(beta + db * 16 + g * 4);
      ushort4 o;
      o.x = f2bf((x[db][0] - mean) * rs * gv.x + bb.x);
      o.y = f2bf((x[db][1] - mean) * rs * gv.y + bb.y);
      o.z = f2bf((x[db][2] - mean) * rs * gv.z + bb.z);
      o.w = f2bf((x[db][3] - mean) * rs * gv.w + bb.w);
      *(ushort4*)(hrow + db * 16 + g * 4) = o;
    }
  }
}

// ---------------------------------------------------------------------------
// Fused vocab projection + entropy, register-transposed, no LDS/barriers.
// ---------------------------------------------------------------------------
__global__ __launch_bounds__(256) void vocab_entropy(
    const unsigned short* __restrict__ h, const unsigned short* __restrict__ Wp,
    const float* __restrict__ bias, float* __restrict__ ent) {
  const int lane = threadIdx.x & 63, w = threadIdx.x >> 6;
  const int c = lane & 15, g = lane >> 4;
  const size_t tok0 = (size_t)blockIdx.x * 128 + w * 32;

  bf16x8 at[2][4];
#pragma unroll
  for (int tf = 0; tf < 2; ++tf)
#pragma unroll
    for (int kk = 0; kk < 4; ++kk)
      at[tf][kk] =
          *(const bf16x8*)(h + (tok0 + tf * 16 + c) * 128 + kk * 32 + g * 8);

  f32x4 acc[16][2] = {};
#pragma unroll
  for (int vb = 0; vb < 16; ++vb)
#pragma unroll
    for (int kk = 0; kk < 4; ++kk) {
      bf16x8 wf = *(const bf16x8*)(Wp + (vb * 4 + kk) * 512 + lane * 8);
      acc[vb][0] = MFMA(wf, at[0][kk], acc[vb][0], 0, 0, 0);
      acc[vb][1] = MFMA(wf, at[1][kk], acc[vb][1], 0, 0, 0);
    }

  const float L2E = 1.4426950408889634f;
#pragma unroll
  for (int tf = 0; tf < 2; ++tf) {
    float m_ = -1e30f;
#pragma unroll
    for (int vb = 0; vb < 16; ++vb) {
      float4 bv = *(const float4*)(bias + vb * 16 + g * 4);
      acc[vb][tf][0] += bv.x; acc[vb][tf][1] += bv.y;
      acc[vb][tf][2] += bv.z; acc[vb][tf][3] += bv.w;
      m_ = fmaxf(m_, fmaxf(fmaxf(acc[vb][tf][0], acc[vb][tf][1]),
                           fmaxf(acc[vb][tf][2], acc[vb][tf][3])));
    }
    m_ = fmaxf(m_, __shfl_xor(m_, 16));
    m_ = fmaxf(m_, __shfl_xor(m_, 32));
    float z_ = 0.f, sx_ = 0.f;
#pragma unroll
    for (int vb = 0; vb < 16; ++vb)
#pragma unroll
      for (int r = 0; r < 4; ++r) {
        float xx = acc[vb][tf][r];
        float e = EXP2((xx - m_) * L2E);
        z_ += e; sx_ += e * xx;
      }
    z_ += __shfl_xor(z_, 16);  z_ += __shfl_xor(z_, 32);
    sx_ += __shfl_xor(sx_, 16); sx_ += __shfl_xor(sx_, 32);
    if (g == 0) ent[tok0 + tf * 16 + c] = m_ + logf(z_) - sx_ / z_;
  }
}

// ---------------------------------------------------------------------------
// MFMA flash attention, register-resident P (round-7 version, verbatim).
// One block (512 thr = 8 waves) per (batch, head).
// ---------------------------------------------------------------------------
__global__ __launch_bounds__(512, 4) void attn_mfma(
    const unsigned short* __restrict__ qkv, unsigned short* __restrict__ obf) {
  __shared__ __bf16 Ks[512 * 40];
  __shared__ __bf16 Vt[32 * 520];

  const int hh = blockIdx.x & 3, bl = blockIdx.x >> 2;
  const int t = threadIdx.x;
  const int lane = t & 63, wv = t >> 6;
  const int c = lane & 15, g = lane >> 4;
  const size_t tok0 = (size_t)bl * 512;

  {
    const unsigned short* kr = qkv + (tok0 + t) * 384 + 128 + hh * 32;
    bf16x8 k0 = *(const bf16x8*)(kr);
    bf16x8 k1 = *(const bf16x8*)(kr + 8);
    bf16x8 k2 = *(const bf16x8*)(kr + 16);
    bf16x8 k3 = *(const bf16x8*)(kr + 24);
    __bf16* kd = Ks + t * 40;
    *(bf16x8*)(kd + 0) = k0;  *(bf16x8*)(kd + 8) = k1;
    *(bf16x8*)(kd + 16) = k2; *(bf16x8*)(kd + 24) = k3;
    const unsigned short* vr = kr + 128;
    bf16x8 v0 = *(const bf16x8*)(vr);
    bf16x8 v1 = *(const bf16x8*)(vr + 8);
    bf16x8 v2 = *(const bf16x8*)(vr + 16);
    bf16x8 v3 = *(const bf16x8*)(vr + 24);
#pragma unroll
    for (int i = 0; i < 8; ++i) {
      Vt[(i)      * 520 + t] = v0[i];
      Vt[(i + 8)  * 520 + t] = v1[i];
      Vt[(i + 16) * 520 + t] = v2[i];
      Vt[(i + 24) * 520 + t] = v3[i];
    }
  }

  bf16x8 qb[4];
  {
    const unsigned short* qp = qkv + (tok0 + wv * 64) * 384 + hh * 32;
#pragma unroll
    for (int qf = 0; qf < 4; ++qf)
      qb[qf] = *(const bf16x8*)(qp + (size_t)(qf * 16 + c) * 384 + g * 8);
  }
  __syncthreads();

  f32x4 ot[4][2] = {};
  float l[4] = {0.f, 0.f, 0.f, 0.f};
  const f32x4 zz = {0.f, 0.f, 0.f, 0.f};

  for (int kt = 0; kt < 8; ++kt) {
    bf16x8 ka[4];
#pragma unroll
    for (int kf = 0; kf < 4; ++kf)
      ka[kf] = *(const bf16x8*)&Ks[(kt * 64 + kf * 16 + c) * 40 + g * 8];
    bf16x8 vb[2][2];
#pragma unroll
    for (int hf = 0; hf < 2; ++hf)
#pragma unroll
      for (int ksl = 0; ksl < 2; ++ksl)
        vb[hf][ksl] =
            *(const bf16x8*)&Vt[(hf * 16 + c) * 520 + kt * 64 + ksl * 32 + g * 8];

#pragma unroll
    for (int qf = 0; qf < 4; ++qf) {
      f32x4 sA = MFMA(ka[0], qb[qf], zz, 0, 0, 0);
      f32x4 sB = MFMA(ka[1], qb[qf], zz, 0, 0, 0);
      f32x4 sC = MFMA(ka[2], qb[qf], zz, 0, 0, 0);
      f32x4 sD = MFMA(ka[3], qb[qf], zz, 0, 0, 0);

      {
        float pa0 = EXP2(sA[0]), pa1 = EXP2(sA[1]);
        float pa2 = EXP2(sA[2]), pa3 = EXP2(sA[3]);
        float pb0 = EXP2(sB[0]), pb1 = EXP2(sB[1]);
        float pb2 = EXP2(sB[2]), pb3 = EXP2(sB[3]);
        l[qf] += ((pa0 + pa1) + (pa2 + pa3)) + ((pb0 + pb1) + (pb2 + pb3));
        unsigned int w00 = cvtpk_bf16(pa0, pa1), w01 = cvtpk_bf16(pa2, pa3);
        unsigned int w10 = cvtpk_bf16(pb0, pb1), w11 = cvtpk_bf16(pb2, pb3);
        plswap32(w00, w10); plswap16(w00, w10);
        plswap32(w01, w11); plswap16(w01, w11);
        union { unsigned int u[4]; bf16x8 v; } pk;
        pk.u[0] = w00; pk.u[1] = w01; pk.u[2] = w10; pk.u[3] = w11;
        ot[qf][0] = MFMA(vb[0][0], pk.v, ot[qf][0], 0, 0, 0);
        ot[qf][1] = MFMA(vb[1][0], pk.v, ot[qf][1], 0, 0, 0);
      }
      {
        float pa0 = EXP2(sC[0]), pa1 = EXP2(sC[1]);
        float pa2 = EXP2(sC[2]), pa3 = EXP2(sC[3]);
        float pb0 = EXP2(sD[0]), pb1 = EXP2(sD[1]);
        float pb2 = EXP2(sD[2]), pb3 = EXP2(sD[3]);
        l[qf] += ((pa0 + pa1) + (pa2 + pa3)) + ((pb0 + pb1) + (pb2 + pb3));
        unsigned int w00 = cvtpk_bf16(pa0, pa1), w01 = cvtpk_bf16(pa2, pa3);
        unsigned int w10 = cvtpk_bf16(pb0, pb1), w11 = cvtpk_bf16(pb2, pb3);
        plswap32(w00, w10); plswap16(w00, w10);
        plswap32(w01, w11); plswap16(w01, w11);
        union { unsigned int u[4]; bf16x8 v; } pk;
        pk.u[0] = w00; pk.u[1] = w01; pk.u[2] = w10; pk.u[3] = w11;
        ot[qf][0] = MFMA(vb[0][1], pk.v, ot[qf][0], 0, 0, 0);
        ot[qf][1] = MFMA(vb[1][1], pk.v, ot[qf][1], 0, 0, 0);
      }
    }
  }

#pragma unroll
  for (int qf = 0; qf < 4; ++qf) {
    l[qf] += __shfl_xor(l[qf], 16);
    l[qf] += __shfl_xor(l[qf], 32);
  }
#pragma unroll
  for (int qf = 0; qf < 4; ++qf) {
    float rl = 1.0f / l[qf];
#pragma unroll
    for (int hf = 0; hf < 2; ++hf) {
      ushort4 pk;
      pk.x = f2bf(ot[qf][hf][0] * rl);
      pk.y = f2bf(ot[qf][hf][1] * rl);
      pk.z = f2bf(ot[qf][hf][2] * rl);
      pk.w = f2bf(ot[qf][hf][3] * rl);
      *(ushort4*)(obf + (tok0 + wv * 64 + qf * 16 + c) * 128 + hh * 32 +
                  hf * 16 + g * 4) = pk;
    }
  }
}

// ---------------------------------------------------------------------------
__global__ __launch_bounds__(64) void avg_entropy_kernel(
    const float* __restrict__ ent, float* __restrict__ out) {
  int s = blockIdx.x, lane = threadIdx.x;
  float a = 0.f;
  for (int b = lane; b < 256; b += 64) a += ent[(size_t)b * 512 + s];
#pragma unroll
  for (int off = 32; off; off >>= 1) a += __shfl_xor(a, off);
  if (lane == 0) out[s] = a * 0.00390625f;
}

__global__ __launch_bounds__(512) void seg_kernel(float* out) {
  __shared__ int cs[512];
  int i = threadIdx.x;
  float e = out[i];
  cs[i] = (i >= 1 && e > 4.0f) ? 1 : 0;
  __syncthreads();
  for (int off = 1; off < 512; off <<= 1) {
    int v = (i >= off) ? cs[i - off] : 0;
    __syncthreads();
    cs[i] += v;
    __syncthreads();
  }
  out[512 + i] = (float)cs[i];
}

// ---------------------------------------------------------------------------
extern "C" void kernel_launch(void* const* d_in, const int* in_sizes, int n_in,
                              void* d_out, int out_size, void* d_ws,
                              size_t ws_size, hipStream_t stream) {
  (void)in_sizes; (void)n_in; (void)out_size; (void)ws_size;
  const int*   input_bytes = (const int*)d_in[0];
  const float* emb    = (const float*)d_in[1];
  const float* pos    = (const float*)d_in[2];
  const float* ln_g   = (const float*)d_in[3];
  const float* ln_b   = (const float*)d_in[4];
  const float* attn_w = (const float*)d_in[5];
  const float* attn_b = (const float*)d_in[6];
  const float* out_w  = (const float*)d_in[7];
  const float* out_b  = (const float*)d_in[8];
  const float* ff1_w  = (const float*)d_in[9];
  const float* ff1_b  = (const float*)d_in[10];
  const float* ff2_w  = (const float*)d_in[11];
  const float* ff2_b  = (const float*)d_in[12];
  const float* n1_g   = (const float*)d_in[13];
  const float* n1_b   = (const float*)d_in[14];
  const float* n2_g   = (const float*)d_in[15];
  const float* n2_b   = (const float*)d_in[16];
  const float* proj_w = (const float*)d_in[17];
  const float* proj_b = (const float*)d_in[18];

  char* ws = (char*)d_ws;
  unsigned short* hbf  = (unsigned short*)(ws);                // 32 MB
  unsigned short* obf  = (unsigned short*)(ws + 33554432);     // 32 MB
  unsigned short* qkvc = (unsigned short*)(ws + 67108864);     // 96 MB
  unsigned short* wbf  = (unsigned short*)(ws + 167772160);    // ~0.85 MB
  float*          absb = (float*)(ws + 168624128);             // 3 KB
  float*          entb = (float*)(ws + 168628224);             // 0.5 MB

  unsigned short* attnwA = wbf;
  unsigned short* outwA  = wbf + 98304;
  unsigned short* w1A    = wbf + 131072;
  unsigned short* w2A    = wbf + 262144;
  unsigned short* projA  = wbf + 393216;

  conv_attn_wA<<<384, 256, 0, stream>>>(attn_w, attnwA);
  conv_attn_b<<<3, 256, 0, stream>>>(attn_b, absb);
  for (int l = 0; l < 2; ++l) {
    conv_permA<<<64, 256, 0, stream>>>(out_w + l * 16384, outwA + l * 16384,
                                       128, 16384);
    conv_permA<<<256, 256, 0, stream>>>(ff1_w + l * 65536, w1A + l * 65536,
                                        128, 65536);
    conv_permA<<<256, 256, 0, stream>>>(ff2_w + l * 65536, w2A + l * 65536,
                                        512, 65536);
  }
  conv_permA<<<128, 256, 0, stream>>>(proj_w, projA, 128, 32768);

  embed_ln<<<32768, 256, 0, stream>>>(input_bytes, emb, pos, ln_g, ln_b, hbf);

  for (int l = 0; l < 2; ++l) {
    qkv_reg<<<1024, 256, 0, stream>>>(hbf, attnwA + l * 49152, absb + l * 384,
                                      qkvc);
    attn_mfma<<<1024, 512, 0, stream>>>(qkvc, obf);
    oproj_ln<<<1024, 256, 0, stream>>>(obf, outwA + l * 16384, out_b + l * 128,
                                       hbf, n1_g + l * 128, n1_b + l * 128);
    ffn_reg<<<1024, 256, 0, stream>>>(hbf, w1A + l * 65536, ff1_b + l * 512,
                                      w2A + l * 65536, ff2_b + l * 128,
                                      n2_g + l * 128, n2_b + l * 128);
  }

  vocab_entropy<<<1024, 256, 0, stream>>>(hbf, projA, proj_b, entb);
  avg_entropy_kernel<<<512, 64, 0, stream>>>(entb, (float*)d_out);
  seg_kernel<<<1, 512, 0, stream>>>((float*)d_out);
}

// Round 10
// 438.008 us; speedup vs baseline: 3.0473x; 1.3051x over previous
//
#include <hip/hip_runtime.h>

// ---------------------------------------------------------------------------
// EntropyCalculator: 2-layer post-norm transformer encoder + entropy head.
// B=256 S=512 D=128 H=4 HD=32 FF=512 V=256
// Fused QKV+attention (register-transposed QKV, frag-linear LDS);
// register-transposed barrier-free oproj/FFN/entropy.
// ---------------------------------------------------------------------------

typedef __bf16 bf16x8 __attribute__((ext_vector_type(8)));
typedef float  f32x4  __attribute__((ext_vector_type(4)));

__device__ __forceinline__ unsigned short f2bf(float f) {
  union { float f; unsigned int u; } c; c.f = f;
  unsigned int u = c.u;
  u += 0x7FFFu + ((u >> 16) & 1u);   // round-to-nearest-even
  return (unsigned short)(u >> 16);
}
__device__ __forceinline__ float bf2f(unsigned short u) {
  union { unsigned int u; float f; } c; c.u = ((unsigned int)u) << 16;
  return c.f;
}

__device__ __forceinline__ float EXP2(float x) {
#if __has_builtin(__builtin_amdgcn_exp2f)
  return __builtin_amdgcn_exp2f(x);
#else
  return exp2f(x);
#endif
}

__device__ __forceinline__ unsigned int cvtpk_bf16(float lo, float hi) {
  unsigned int r;
  asm("v_cvt_pk_bf16_f32 %0, %1, %2" : "=v"(r) : "v"(lo), "v"(hi));
  return r;
}
__device__ __forceinline__ void plswap32(unsigned int& a, unsigned int& b) {
  asm("v_permlane32_swap_b32 %0, %1" : "+v"(a), "+v"(b));
}
__device__ __forceinline__ void plswap16(unsigned int& a, unsigned int& b) {
  asm("v_permlane16_swap_b32 %0, %1" : "+v"(a), "+v"(b));
}
// Merge two mfma outputs (rows r0..15 / r16..31 on g*4+reg, col on c) into an
// operand frag: lane(c,g) = M[idx=c][32-row dim packed g*8..g*8+7] (verified
// dance: attn-P r3, ffn-G r7).
__device__ __forceinline__ bf16x8 packfrag(f32x4 a, f32x4 b) {
  unsigned int w00 = cvtpk_bf16(a[0], a[1]), w01 = cvtpk_bf16(a[2], a[3]);
  unsigned int w10 = cvtpk_bf16(b[0], b[1]), w11 = cvtpk_bf16(b[2], b[3]);
  plswap32(w00, w10); plswap16(w00, w10);
  plswap32(w01, w11); plswap16(w01, w11);
  union { unsigned int u[4]; bf16x8 v; } pk;
  pk.u[0] = w00; pk.u[1] = w01; pk.u[2] = w10; pk.u[3] = w11;
  return pk.v;
}

#define MFMA __builtin_amdgcn_mfma_f32_16x16x32_bf16

// ---------------------------------------------------------------------------
// weight conversions
// ---------------------------------------------------------------------------
// [N][K] f32 -> bf16 A-operand fragment lane order:
// frag (nb=row>>4, kb=k>>5) is 1KB contiguous; within frag, lane l=(g*16+c)
// holds row nb*16+c, k kb*32+g*8..+7 at halfword offset l*8.
__global__ void conv_permA(const float* __restrict__ src,
                           unsigned short* __restrict__ dst, int K, int n) {
  int i = blockIdx.x * 256 + threadIdx.x;
  if (i >= n) return;
  int row = i / K, k = i - row * K;
  int frag = (row >> 4) * (K >> 5) + (k >> 5);
  int d = frag * 512 + ((k >> 3) & 3) * 128 + (row & 15) * 8 + (k & 7);
  dst[d] = f2bf(src[i]);
}

// attn_w [2][384][128] -> per (layer, head, mat q/k/v) A-frag arrays of
// 2 db x 4 kk frags (4096 hw each).  Q rows pre-scaled.
#define QSCALE 0.2550602989892646f
__global__ void conv_attn_headA(const float* __restrict__ src,
                                unsigned short* __restrict__ dst) {
  int i = blockIdx.x * 256 + threadIdx.x;  // 98304
  int l = i / 49152, rem = i - l * 49152;
  int row = rem >> 7, k = rem & 127;
  int mat = row >> 7;            // 0=q 1=k 2=v
  int head = (row >> 5) & 3;
  int dr = row & 31;
  float v = src[i];
  if (mat == 0) v *= QSCALE;
  int d = ((l * 4 + head) * 3 + mat) * 4096 +
          ((dr >> 4) * 4 + (k >> 5)) * 512 + ((k >> 3) & 3) * 128 +
          (dr & 15) * 8 + (k & 7);
  dst[d] = f2bf(v);
}
__global__ void conv_attn_b(const float* __restrict__ src,
                            float* __restrict__ dst) {
  int i = blockIdx.x * 256 + threadIdx.x;  // 768
  if (i < 768) {
    float v = src[i];
    if ((i % 384) < 128) v *= QSCALE;
    dst[i] = v;
  }
}

// ---------------------------------------------------------------------------
// Embedding + LayerNorm -> bf16 residual stream.  One wave per token.
// ---------------------------------------------------------------------------
__global__ __launch_bounds__(256) void embed_ln(
    const int* __restrict__ bytes, const float* __restrict__ emb,
    const float* __restrict__ pos, const float* __restrict__ g,
    const float* __restrict__ bta, unsigned short* __restrict__ hbf) {
  int wv = threadIdx.x >> 6, lane = threadIdx.x & 63;
  int tok = blockIdx.x * 4 + wv;
  int s = tok & 511;
  int bidx = bytes[tok];
  const float* e = emb + (size_t)bidx * 128;
  const float* p = pos + (size_t)s * 128;
  float x0 = e[lane] + p[lane];
  float x1 = e[lane + 64] + p[lane + 64];
  float sum = x0 + x1, ssq = x0 * x0 + x1 * x1;
#pragma unroll
  for (int off = 32; off; off >>= 1) {
    sum += __shfl_xor(sum, off);
    ssq += __shfl_xor(ssq, off);
  }
  float mean = sum * 0.0078125f;
  float var = ssq * 0.0078125f - mean * mean;
  float rs = rsqrtf(var + 1e-5f);
  float y0 = (x0 - mean) * rs * g[lane] + bta[lane];
  float y1 = (x1 - mean) * rs * g[lane + 64] + bta[lane + 64];
  size_t o = (size_t)tok * 128;
  hbf[o + lane] = f2bf(y0); hbf[o + lane + 64] = f2bf(y1);
}

// ---------------------------------------------------------------------------
// Fused QKV + flash attention.  One block (512 thr = 8 waves) per (b, head).
// Phase 1 (per wave, tokens wv*64..+63): at[] token frags of h; compute
//   Q^T=mfma(Wq,at) -> pack -> qb regs; K^T=mfma(Wk,at) -> pack -> Ks LDS;
//   V  =mfma(at,Wv) -> pack -> Vt LDS.  Frag-linear LDS (lane*16B).
// Phase 2: round-7 loop, P register-resident via packfrag, O^T=mfma(Vt,P^T).
// LDS 64KB -> 2 blocks/CU.
// ---------------------------------------------------------------------------
__global__ __launch_bounds__(512, 4) void attn_fused(
    const unsigned short* __restrict__ h, const unsigned short* __restrict__ Wa,
    const float* __restrict__ ab, unsigned short* __restrict__ obf) {
  __shared__ __bf16 Ks[32 * 512];   // 32 key-frags (16 keys x 32 d)
  __shared__ __bf16 Vt[32 * 512];   // [hf*16 + keyblock32] frags (16 d x 32 k)

  const int hh = blockIdx.x & 3, bl = blockIdx.x >> 2;
  const int t = threadIdx.x;
  const int lane = t & 63, wv = t >> 6;
  const int c = lane & 15, g = lane >> 4;
  const size_t tok0 = (size_t)bl * 512;
  const size_t myq = tok0 + wv * 64;

  const unsigned short* Wb = Wa + hh * 3 * 4096;
  const float* bq = ab + hh * 32;
  const float* bk = ab + 128 + hh * 32;
  const float* bv = ab + 256 + hh * 32;

  // token fragments of h (serve Q, K, V)
  bf16x8 at[4][4];
#pragma unroll
  for (int tf = 0; tf < 4; ++tf)
#pragma unroll
    for (int kk = 0; kk < 4; ++kk)
      at[tf][kk] =
          *(const bf16x8*)(h + (myq + tf * 16 + c) * 128 + kk * 32 + g * 8);

  bf16x8 qb[4];
  // ---- Q ----
  {
    f32x4 dd[2][4] = {};
#pragma unroll
    for (int kk = 0; kk < 4; ++kk) {
      bf16x8 w0 = *(const bf16x8*)(Wb + kk * 512 + lane * 8);
      bf16x8 w1 = *(const bf16x8*)(Wb + (4 + kk) * 512 + lane * 8);
#pragma unroll
      for (int tf = 0; tf < 4; ++tf) {
        dd[0][tf] = MFMA(w0, at[tf][kk], dd[0][tf], 0, 0, 0);
        dd[1][tf] = MFMA(w1, at[tf][kk], dd[1][tf], 0, 0, 0);
      }
    }
    float4 b0 = *(const float4*)(bq + g * 4);
    float4 b1 = *(const float4*)(bq + 16 + g * 4);
#pragma unroll
    for (int tf = 0; tf < 4; ++tf) {
      dd[0][tf][0] += b0.x; dd[0][tf][1] += b0.y;
      dd[0][tf][2] += b0.z; dd[0][tf][3] += b0.w;
      dd[1][tf][0] += b1.x; dd[1][tf][1] += b1.y;
      dd[1][tf][2] += b1.z; dd[1][tf][3] += b1.w;
      qb[tf] = packfrag(dd[0][tf], dd[1][tf]);
    }
  }
  // ---- K ----
  {
    const unsigned short* W = Wb + 4096;
    f32x4 dd[2][4] = {};
#pragma unroll
    for (int kk = 0; kk < 4; ++kk) {
      bf16x8 w0 = *(const bf16x8*)(W + kk * 512 + lane * 8);
      bf16x8 w1 = *(const bf16x8*)(W + (4 + kk) * 512 + lane * 8);
#pragma unroll
      for (int tf = 0; tf < 4; ++tf) {
        dd[0][tf] = MFMA(w0, at[tf][kk], dd[0][tf], 0, 0, 0);
        dd[1][tf] = MFMA(w1, at[tf][kk], dd[1][tf], 0, 0, 0);
      }
    }
    float4 b0 = *(const float4*)(bk + g * 4);
    float4 b1 = *(const float4*)(bk + 16 + g * 4);
#pragma unroll
    for (int tf = 0; tf < 4; ++tf) {
      dd[0][tf][0] += b0.x; dd[0][tf][1] += b0.y;
      dd[0][tf][2] += b0.z; dd[0][tf][3] += b0.w;
      dd[1][tf][0] += b1.x; dd[1][tf][1] += b1.y;
      dd[1][tf][2] += b1.z; dd[1][tf][3] += b1.w;
      *(bf16x8*)&Ks[(wv * 4 + tf) * 512 + lane * 8] =
          packfrag(dd[0][tf], dd[1][tf]);
    }
  }
  // ---- V (per hf half to cap registers) ----
  {
    const unsigned short* W = Wb + 8192;
    float v0 = bv[c], v1 = bv[16 + c];
#pragma unroll
    for (int hf = 0; hf < 2; ++hf) {
      f32x4 dd[4] = {};
#pragma unroll
      for (int kk = 0; kk < 4; ++kk) {
        bf16x8 wvf = *(const bf16x8*)(W + (hf * 4 + kk) * 512 + lane * 8);
#pragma unroll
        for (int tf = 0; tf < 4; ++tf)
          dd[tf] = MFMA(at[tf][kk], wvf, dd[tf], 0, 0, 0);
      }
      float bvv = hf ? v1 : v0;
#pragma unroll
      for (int tf = 0; tf < 4; ++tf) {
        dd[tf][0] += bvv; dd[tf][1] += bvv;
        dd[tf][2] += bvv; dd[tf][3] += bvv;
      }
#pragma unroll
      for (int pr = 0; pr < 2; ++pr)
        *(bf16x8*)&Vt[(hf * 16 + wv * 2 + pr) * 512 + lane * 8] =
            packfrag(dd[2 * pr], dd[2 * pr + 1]);
    }
  }
  __syncthreads();

  // ---- phase 2: flash attention over 8 key tiles of 64 ----
  f32x4 ot[4][2] = {};
  float l[4] = {0.f, 0.f, 0.f, 0.f};
  const f32x4 zz = {0.f, 0.f, 0.f, 0.f};

  for (int kt = 0; kt < 8; ++kt) {
    bf16x8 ka[4];
#pragma unroll
    for (int kf = 0; kf < 4; ++kf)
      ka[kf] = *(const bf16x8*)&Ks[(kt * 4 + kf) * 512 + lane * 8];
    bf16x8 vb2[2][2];
#pragma unroll
    for (int hf = 0; hf < 2; ++hf)
#pragma unroll
      for (int ksl = 0; ksl < 2; ++ksl)
        vb2[hf][ksl] =
            *(const bf16x8*)&Vt[(hf * 16 + kt * 2 + ksl) * 512 + lane * 8];

#pragma unroll
    for (int qf = 0; qf < 4; ++qf) {
      f32x4 sA = MFMA(ka[0], qb[qf], zz, 0, 0, 0);
      f32x4 sB = MFMA(ka[1], qb[qf], zz, 0, 0, 0);
      f32x4 sC = MFMA(ka[2], qb[qf], zz, 0, 0, 0);
      f32x4 sD = MFMA(ka[3], qb[qf], zz, 0, 0, 0);

      {
        float pa0 = EXP2(sA[0]), pa1 = EXP2(sA[1]);
        float pa2 = EXP2(sA[2]), pa3 = EXP2(sA[3]);
        float pb0 = EXP2(sB[0]), pb1 = EXP2(sB[1]);
        float pb2 = EXP2(sB[2]), pb3 = EXP2(sB[3]);
        l[qf] += ((pa0 + pa1) + (pa2 + pa3)) + ((pb0 + pb1) + (pb2 + pb3));
        f32x4 pa = {pa0, pa1, pa2, pa3};
        f32x4 pb = {pb0, pb1, pb2, pb3};
        bf16x8 pk = packfrag(pa, pb);
        ot[qf][0] = MFMA(vb2[0][0], pk, ot[qf][0], 0, 0, 0);
        ot[qf][1] = MFMA(vb2[1][0], pk, ot[qf][1], 0, 0, 0);
      }
      {
        float pa0 = EXP2(sC[0]), pa1 = EXP2(sC[1]);
        float pa2 = EXP2(sC[2]), pa3 = EXP2(sC[3]);
        float pb0 = EXP2(sD[0]), pb1 = EXP2(sD[1]);
        float pb2 = EXP2(sD[2]), pb3 = EXP2(sD[3]);
        l[qf] += ((pa0 + pa1) + (pa2 + pa3)) + ((pb0 + pb1) + (pb2 + pb3));
        f32x4 pa = {pa0, pa1, pa2, pa3};
        f32x4 pb = {pb0, pb1, pb2, pb3};
        bf16x8 pk = packfrag(pa, pb);
        ot[qf][0] = MFMA(vb2[0][1], pk, ot[qf][0], 0, 0, 0);
        ot[qf][1] = MFMA(vb2[1][1], pk, ot[qf][1], 0, 0, 0);
      }
    }
  }

#pragma unroll
  for (int qf = 0; qf < 4; ++qf) {
    l[qf] += __shfl_xor(l[qf], 16);
    l[qf] += __shfl_xor(l[qf], 32);
  }
#pragma unroll
  for (int qf = 0; qf < 4; ++qf) {
    float rl = 1.0f / l[qf];
#pragma unroll
    for (int hf = 0; hf < 2; ++hf) {
      ushort4 pk;
      pk.x = f2bf(ot[qf][hf][0] * rl);
      pk.y = f2bf(ot[qf][hf][1] * rl);
      pk.z = f2bf(ot[qf][hf][2] * rl);
      pk.w = f2bf(ot[qf][hf][3] * rl);
      *(ushort4*)(obf + (myq + qf * 16 + c) * 128 + hh * 32 + hf * 16 +
                  g * 4) = pk;
    }
  }
}

// ---------------------------------------------------------------------------
// Fused out-proj + residual + LayerNorm, register-transposed, no LDS/barrier.
// ---------------------------------------------------------------------------
__global__ __launch_bounds__(256) void oproj_ln(
    const unsigned short* __restrict__ A, const unsigned short* __restrict__ Wp,
    const float* __restrict__ bias, unsigned short* __restrict__ h,
    const float* __restrict__ gamma, const float* __restrict__ beta) {
  const int lane = threadIdx.x & 63, w = threadIdx.x >> 6;
  const int c = lane & 15, g = lane >> 4;
  const size_t tok0 = (size_t)blockIdx.x * 128 + w * 32;

  bf16x8 at[2][4];
#pragma unroll
  for (int tf = 0; tf < 2; ++tf)
#pragma unroll
    for (int kk = 0; kk < 4; ++kk)
      at[tf][kk] =
          *(const bf16x8*)(A + (tok0 + tf * 16 + c) * 128 + kk * 32 + g * 8);

  f32x4 acc[8][2] = {};
#pragma unroll
  for (int db = 0; db < 8; ++db)
#pragma unroll
    for (int kk = 0; kk < 4; ++kk) {
      bf16x8 wf = *(const bf16x8*)(Wp + (db * 4 + kk) * 512 + lane * 8);
      acc[db][0] = MFMA(wf, at[0][kk], acc[db][0], 0, 0, 0);
      acc[db][1] = MFMA(wf, at[1][kk], acc[db][1], 0, 0, 0);
    }

#pragma unroll
  for (int tf = 0; tf < 2; ++tf) {
    unsigned short* hrow = h + (tok0 + tf * 16 + c) * 128;
    float x[8][4];
    float s_ = 0.f, q_ = 0.f;
#pragma unroll
    for (int db = 0; db < 8; ++db) {
      float4 bvv = *(const float4*)(bias + db * 16 + g * 4);
      ushort4 rv = *(const ushort4*)(hrow + db * 16 + g * 4);
      x[db][0] = acc[db][tf][0] + bvv.x + bf2f(rv.x);
      x[db][1] = acc[db][tf][1] + bvv.y + bf2f(rv.y);
      x[db][2] = acc[db][tf][2] + bvv.z + bf2f(rv.z);
      x[db][3] = acc[db][tf][3] + bvv.w + bf2f(rv.w);
#pragma unroll
      for (int r = 0; r < 4; ++r) { s_ += x[db][r]; q_ += x[db][r] * x[db][r]; }
    }
    s_ += __shfl_xor(s_, 16); s_ += __shfl_xor(s_, 32);
    q_ += __shfl_xor(q_, 16); q_ += __shfl_xor(q_, 32);
    float mean = s_ * 0.0078125f;
    float var = q_ * 0.0078125f - mean * mean;
    float rs = rsqrtf(var + 1e-5f);
#pragma unroll
    for (int db = 0; db < 8; ++db) {
      float4 gv = *(const float4*)(gamma + db * 16 + g * 4);
      float4 bb = *(const float4*)(beta + db * 16 + g * 4);
      ushort4 o;
      o.x = f2bf((x[db][0] - mean) * rs * gv.x + bb.x);
      o.y = f2bf((x[db][1] - mean) * rs * gv.y + bb.y);
      o.z = f2bf((x[db][2] - mean) * rs * gv.z + bb.z);
      o.w = f2bf((x[db][3] - mean) * rs * gv.w + bb.w);
      *(ushort4*)(hrow + db * 16 + g * 4) = o;
    }
  }
}

// ---------------------------------------------------------------------------
// Fused FFN, register-transposed, G never leaves registers, no LDS/barriers.
// ---------------------------------------------------------------------------
__global__ __launch_bounds__(256) void ffn_reg(
    unsigned short* __restrict__ h, const unsigned short* __restrict__ W1p,
    const float* __restrict__ b1, const unsigned short* __restrict__ W2p,
    const float* __restrict__ b2, const float* __restrict__ gamma,
    const float* __restrict__ beta) {
  const int lane = threadIdx.x & 63, w = threadIdx.x >> 6;
  const int c = lane & 15, g = lane >> 4;
  const size_t tok0 = (size_t)blockIdx.x * 128 + w * 32;

  bf16x8 at[2][4];
#pragma unroll
  for (int tf = 0; tf < 2; ++tf)
#pragma unroll
    for (int kk = 0; kk < 4; ++kk)
      at[tf][kk] =
          *(const bf16x8*)(h + (tok0 + tf * 16 + c) * 128 + kk * 32 + g * 8);

  f32x4 acc[8][2] = {};
  for (int s = 0; s < 16; ++s) {          // 16 slices of 32 ff
    f32x4 d1[2][2] = {};                  // [ffhalf][tf]
#pragma unroll
    for (int kk = 0; kk < 4; ++kk) {
      bf16x8 wa = *(const bf16x8*)(W1p + ((2 * s) * 4 + kk) * 512 + lane * 8);
      bf16x8 wb = *(const bf16x8*)(W1p + ((2 * s + 1) * 4 + kk) * 512 + lane * 8);
      d1[0][0] = MFMA(wa, at[0][kk], d1[0][0], 0, 0, 0);
      d1[0][1] = MFMA(wa, at[1][kk], d1[0][1], 0, 0, 0);
      d1[1][0] = MFMA(wb, at[0][kk], d1[1][0], 0, 0, 0);
      d1[1][1] = MFMA(wb, at[1][kk], d1[1][1], 0, 0, 0);
    }
    float4 bva = *(const float4*)(b1 + s * 32 + g * 4);
    float4 bvb = *(const float4*)(b1 + s * 32 + 16 + g * 4);
    bf16x8 gp[2];
#pragma unroll
    for (int tf = 0; tf < 2; ++tf) {
      f32x4 pa, pb;
      pa[0] = fmaxf(d1[0][tf][0] + bva.x, 0.f);
      pa[1] = fmaxf(d1[0][tf][1] + bva.y, 0.f);
      pa[2] = fmaxf(d1[0][tf][2] + bva.z, 0.f);
      pa[3] = fmaxf(d1[0][tf][3] + bva.w, 0.f);
      pb[0] = fmaxf(d1[1][tf][0] + bvb.x, 0.f);
      pb[1] = fmaxf(d1[1][tf][1] + bvb.y, 0.f);
      pb[2] = fmaxf(d1[1][tf][2] + bvb.z, 0.f);
      pb[3] = fmaxf(d1[1][tf][3] + bvb.w, 0.f);
      gp[tf] = packfrag(pa, pb);
    }
#pragma unroll
    for (int db = 0; db < 8; ++db) {
      bf16x8 w2 = *(const bf16x8*)(W2p + (db * 16 + s) * 512 + lane * 8);
      acc[db][0] = MFMA(w2, gp[0], acc[db][0], 0, 0, 0);
      acc[db][1] = MFMA(w2, gp[1], acc[db][1], 0, 0, 0);
    }
  }

#pragma unroll
  for (int tf = 0; tf < 2; ++tf) {
    unsigned short* hrow = h + (tok0 + tf * 16 + c) * 128;
    float x[8][4];
    float s_ = 0.f, q_ = 0.f;
#pragma unroll
    for (int db = 0; db < 8; ++db) {
      float4 bvv = *(const float4*)(b2 + db * 16 + g * 4);
      ushort4 rv = *(const ushort4*)(hrow + db * 16 + g * 4);
      x[db][0] = acc[db][tf][0] + bvv.x + bf2f(rv.x);
      x[db][1] = acc[db][tf][1] + bvv.y + bf2f(rv.y);
      x[db][2] = acc[db][tf][2] + bvv.z + bf2f(rv.z);
      x[db][3] = acc[db][tf][3] + bvv.w + bf2f(rv.w);
#pragma unroll
      for (int r = 0; r < 4; ++r) { s_ += x[db][r]; q_ += x[db][r] * x[db][r]; }
    }
    s_ += __shfl_xor(s_, 16); s_ += __shfl_xor(s_, 32);
    q_ += __shfl_xor(q_, 16); q_ += __shfl_xor(q_, 32);
    float mean = s_ * 0.0078125f;
    float var = q_ * 0.0078125f - mean * mean;
    float rs = rsqrtf(var + 1e-5f);
#pragma unroll
    for (int db = 0; db < 8; ++db) {
      float4 gv = *(const float4*)(gamma + db * 16 + g * 4);
      float4 bb = *(const float4*)(beta + db * 16 + g * 4);
      ushort4 o;
      o.x = f2bf((x[db][0] - mean) * rs * gv.x + bb.x);
      o.y = f2bf((x[db][1] - mean) * rs * gv.y + bb.y);
      o.z = f2bf((x[db][2] - mean) * rs * gv.z + bb.z);
      o.w = f2bf((x[db][3] - mean) * rs * gv.w + bb.w);
      *(ushort4*)(hrow + db * 16 + g * 4) = o;
    }
  }
}

// ---------------------------------------------------------------------------
// Fused vocab projection + entropy, register-transposed, no LDS/barriers.
// ---------------------------------------------------------------------------
__global__ __launch_bounds__(256) void vocab_entropy(
    const unsigned short* __restrict__ h, const unsigned short* __restrict__ Wp,
    const float* __restrict__ bias, float* __restrict__ ent) {
  const int lane = threadIdx.x & 63, w = threadIdx.x >> 6;
  const int c = lane & 15, g = lane >> 4;
  const size_t tok0 = (size_t)blockIdx.x * 128 + w * 32;

  bf16x8 at[2][4];
#pragma unroll
  for (int tf = 0; tf < 2; ++tf)
#pragma unroll
    for (int kk = 0; kk < 4; ++kk)
      at[tf][kk] =
          *(const bf16x8*)(h + (tok0 + tf * 16 + c) * 128 + kk * 32 + g * 8);

  f32x4 acc[16][2] = {};
#pragma unroll
  for (int vb = 0; vb < 16; ++vb)
#pragma unroll
    for (int kk = 0; kk < 4; ++kk) {
      bf16x8 wf = *(const bf16x8*)(Wp + (vb * 4 + kk) * 512 + lane * 8);
      acc[vb][0] = MFMA(wf, at[0][kk], acc[vb][0], 0, 0, 0);
      acc[vb][1] = MFMA(wf, at[1][kk], acc[vb][1], 0, 0, 0);
    }

  const float L2E = 1.4426950408889634f;
#pragma unroll
  for (int tf = 0; tf < 2; ++tf) {
    float m_ = -1e30f;
#pragma unroll
    for (int vb = 0; vb < 16; ++vb) {
      float4 bvv = *(const float4*)(bias + vb * 16 + g * 4);
      acc[vb][tf][0] += bvv.x; acc[vb][tf][1] += bvv.y;
      acc[vb][tf][2] += bvv.z; acc[vb][tf][3] += bvv.w;
      m_ = fmaxf(m_, fmaxf(fmaxf(acc[vb][tf][0], acc[vb][tf][1]),
                           fmaxf(acc[vb][tf][2], acc[vb][tf][3])));
    }
    m_ = fmaxf(m_, __shfl_xor(m_, 16));
    m_ = fmaxf(m_, __shfl_xor(m_, 32));
    float z_ = 0.f, sx_ = 0.f;
#pragma unroll
    for (int vb = 0; vb < 16; ++vb)
#pragma unroll
      for (int r = 0; r < 4; ++r) {
        float xx = acc[vb][tf][r];
        float e = EXP2((xx - m_) * L2E);
        z_ += e; sx_ += e * xx;
      }
    z_ += __shfl_xor(z_, 16);  z_ += __shfl_xor(z_, 32);
    sx_ += __shfl_xor(sx_, 16); sx_ += __shfl_xor(sx_, 32);
    if (g == 0) ent[tok0 + tf * 16 + c] = m_ + logf(z_) - sx_ / z_;
  }
}

// ---------------------------------------------------------------------------
__global__ __launch_bounds__(64) void avg_entropy_kernel(
    const float* __restrict__ ent, float* __restrict__ out) {
  int s = blockIdx.x, lane = threadIdx.x;
  float a = 0.f;
  for (int b = lane; b < 256; b += 64) a += ent[(size_t)b * 512 + s];
#pragma unroll
  for (int off = 32; off; off >>= 1) a += __shfl_xor(a, off);
  if (lane == 0) out[s] = a * 0.00390625f;
}

__global__ __launch_bounds__(512) void seg_kernel(float* out) {
  __shared__ int cs[512];
  int i = threadIdx.x;
  float e = out[i];
  cs[i] = (i >= 1 && e > 4.0f) ? 1 : 0;
  __syncthreads();
  for (int off = 1; off < 512; off <<= 1) {
    int v = (i >= off) ? cs[i - off] : 0;
    __syncthreads();
    cs[i] += v;
    __syncthreads();
  }
  out[512 + i] = (float)cs[i];
}

// ---------------------------------------------------------------------------
extern "C" void kernel_launch(void* const* d_in, const int* in_sizes, int n_in,
                              void* d_out, int out_size, void* d_ws,
                              size_t ws_size, hipStream_t stream) {
  (void)in_sizes; (void)n_in; (void)out_size; (void)ws_size;
  const int*   input_bytes = (const int*)d_in[0];
  const float* emb    = (const float*)d_in[1];
  const float* pos    = (const float*)d_in[2];
  const float* ln_g   = (const float*)d_in[3];
  const float* ln_b   = (const float*)d_in[4];
  const float* attn_w = (const float*)d_in[5];
  const float* attn_b = (const float*)d_in[6];
  const float* out_w  = (const float*)d_in[7];
  const float* out_b  = (const float*)d_in[8];
  const float* ff1_w  = (const float*)d_in[9];
  const float* ff1_b  = (const float*)d_in[10];
  const float* ff2_w  = (const float*)d_in[11];
  const float* ff2_b  = (const float*)d_in[12];
  const float* n1_g   = (const float*)d_in[13];
  const float* n1_b   = (const float*)d_in[14];
  const float* n2_g   = (const float*)d_in[15];
  const float* n2_b   = (const float*)d_in[16];
  const float* proj_w = (const float*)d_in[17];
  const float* proj_b = (const float*)d_in[18];

  char* ws = (char*)d_ws;
  unsigned short* hbf  = (unsigned short*)(ws);                // 32 MB
  unsigned short* obf  = (unsigned short*)(ws + 33554432);     // 32 MB
  unsigned short* wbf  = (unsigned short*)(ws + 67108864);     // ~0.85 MB
  float*          absb = (float*)(ws + 68157440);              // 3 KB
  float*          entb = (float*)(ws + 68161536);              // 0.5 MB

  unsigned short* attnA = wbf;
  unsigned short* outwA = wbf + 98304;
  unsigned short* w1A   = wbf + 131072;
  unsigned short* w2A   = wbf + 262144;
  unsigned short* projA = wbf + 393216;

  conv_attn_headA<<<384, 256, 0, stream>>>(attn_w, attnA);
  conv_attn_b<<<3, 256, 0, stream>>>(attn_b, absb);
  for (int l = 0; l < 2; ++l) {
    conv_permA<<<64, 256, 0, stream>>>(out_w + l * 16384, outwA + l * 16384,
                                       128, 16384);
    conv_permA<<<256, 256, 0, stream>>>(ff1_w + l * 65536, w1A + l * 65536,
                                        128, 65536);
    conv_permA<<<256, 256, 0, stream>>>(ff2_w + l * 65536, w2A + l * 65536,
                                        512, 65536);
  }
  conv_permA<<<128, 256, 0, stream>>>(proj_w, projA, 128, 32768);

  embed_ln<<<32768, 256, 0, stream>>>(input_bytes, emb, pos, ln_g, ln_b, hbf);

  for (int l = 0; l < 2; ++l) {
    attn_fused<<<1024, 512, 0, stream>>>(hbf, attnA + l * 49152,
                                         absb + l * 384, obf);
    oproj_ln<<<1024, 256, 0, stream>>>(obf, outwA + l * 16384, out_b + l * 128,
                                       hbf, n1_g + l * 128, n1_b + l * 128);
    ffn_reg<<<1024, 256, 0, stream>>>(hbf, w1A + l * 65536, ff1_b + l * 512,
                                      w2A + l * 65536, ff2_b + l * 128,
                                      n2_g + l * 128, n2_b + l * 128);
  }

  vocab_entropy<<<1024, 256, 0, stream>>>(hbf, projA, proj_b, entb);
  avg_entropy_kernel<<<512, 64, 0, stream>>>(entb, (float*)d_out);
  seg_kernel<<<1, 512, 0, stream>>>((float*)d_out);
}

// Round 11
// 433.248 us; speedup vs baseline: 3.0807x; 1.0110x over previous
//
#include <hip/hip_runtime.h>

// ---------------------------------------------------------------------------
// EntropyCalculator: 2-layer post-norm transformer encoder + entropy head.
// B=256 S=512 D=128 H=4 HD=32 FF=512 V=256
// Fused QKV+attention (per-tf register-transposed QKV, frag-linear LDS,
// waves_per_eu-pinned regalloc); register-transposed oproj/FFN/entropy.
// ---------------------------------------------------------------------------

typedef __bf16 bf16x8 __attribute__((ext_vector_type(8)));
typedef float  f32x4  __attribute__((ext_vector_type(4)));

__device__ __forceinline__ unsigned short f2bf(float f) {
  union { float f; unsigned int u; } c; c.f = f;
  unsigned int u = c.u;
  u += 0x7FFFu + ((u >> 16) & 1u);   // round-to-nearest-even
  return (unsigned short)(u >> 16);
}
__device__ __forceinline__ float bf2f(unsigned short u) {
  union { unsigned int u; float f; } c; c.u = ((unsigned int)u) << 16;
  return c.f;
}

__device__ __forceinline__ float EXP2(float x) {
#if __has_builtin(__builtin_amdgcn_exp2f)
  return __builtin_amdgcn_exp2f(x);
#else
  return exp2f(x);
#endif
}

__device__ __forceinline__ unsigned int cvtpk_bf16(float lo, float hi) {
  unsigned int r;
  asm("v_cvt_pk_bf16_f32 %0, %1, %2" : "=v"(r) : "v"(lo), "v"(hi));
  return r;
}
__device__ __forceinline__ void plswap32(unsigned int& a, unsigned int& b) {
  asm("v_permlane32_swap_b32 %0, %1" : "+v"(a), "+v"(b));
}
__device__ __forceinline__ void plswap16(unsigned int& a, unsigned int& b) {
  asm("v_permlane16_swap_b32 %0, %1" : "+v"(a), "+v"(b));
}
// Merge two mfma outputs (rows 0..15 / 16..31 on g*4+reg, col on c) into an
// operand frag: lane(c,g) = M[idx=c][32-dim packed g*8..g*8+7].
__device__ __forceinline__ bf16x8 packfrag(f32x4 a, f32x4 b) {
  unsigned int w00 = cvtpk_bf16(a[0], a[1]), w01 = cvtpk_bf16(a[2], a[3]);
  unsigned int w10 = cvtpk_bf16(b[0], b[1]), w11 = cvtpk_bf16(b[2], b[3]);
  plswap32(w00, w10); plswap16(w00, w10);
  plswap32(w01, w11); plswap16(w01, w11);
  union { unsigned int u[4]; bf16x8 v; } pk;
  pk.u[0] = w00; pk.u[1] = w01; pk.u[2] = w10; pk.u[3] = w11;
  return pk.v;
}

#define MFMA __builtin_amdgcn_mfma_f32_16x16x32_bf16

// ---------------------------------------------------------------------------
// weight conversions
// ---------------------------------------------------------------------------
__global__ void conv_permA(const float* __restrict__ src,
                           unsigned short* __restrict__ dst, int K, int n) {
  int i = blockIdx.x * 256 + threadIdx.x;
  if (i >= n) return;
  int row = i / K, k = i - row * K;
  int frag = (row >> 4) * (K >> 5) + (k >> 5);
  int d = frag * 512 + ((k >> 3) & 3) * 128 + (row & 15) * 8 + (k & 7);
  dst[d] = f2bf(src[i]);
}

// attn_w [2][384][128] -> per (layer, head, mat q/k/v) A-frag arrays of
// 2 db x 4 kk frags (4096 hw each).  Q rows pre-scaled.
#define QSCALE 0.2550602989892646f
__global__ void conv_attn_headA(const float* __restrict__ src,
                                unsigned short* __restrict__ dst) {
  int i = blockIdx.x * 256 + threadIdx.x;  // 98304
  int l = i / 49152, rem = i - l * 49152;
  int row = rem >> 7, k = rem & 127;
  int mat = row >> 7;            // 0=q 1=k 2=v
  int head = (row >> 5) & 3;
  int dr = row & 31;
  float v = src[i];
  if (mat == 0) v *= QSCALE;
  int d = ((l * 4 + head) * 3 + mat) * 4096 +
          ((dr >> 4) * 4 + (k >> 5)) * 512 + ((k >> 3) & 3) * 128 +
          (dr & 15) * 8 + (k & 7);
  dst[d] = f2bf(v);
}
__global__ void conv_attn_b(const float* __restrict__ src,
                            float* __restrict__ dst) {
  int i = blockIdx.x * 256 + threadIdx.x;  // 768
  if (i < 768) {
    float v = src[i];
    if ((i % 384) < 128) v *= QSCALE;
    dst[i] = v;
  }
}

// ---------------------------------------------------------------------------
// Embedding + LayerNorm -> bf16 residual stream.  One wave per token.
// ---------------------------------------------------------------------------
__global__ __launch_bounds__(256) void embed_ln(
    const int* __restrict__ bytes, const float* __restrict__ emb,
    const float* __restrict__ pos, const float* __restrict__ g,
    const float* __restrict__ bta, unsigned short* __restrict__ hbf) {
  int wv = threadIdx.x >> 6, lane = threadIdx.x & 63;
  int tok = blockIdx.x * 4 + wv;
  int s = tok & 511;
  int bidx = bytes[tok];
  const float* e = emb + (size_t)bidx * 128;
  const float* p = pos + (size_t)s * 128;
  float x0 = e[lane] + p[lane];
  float x1 = e[lane + 64] + p[lane + 64];
  float sum = x0 + x1, ssq = x0 * x0 + x1 * x1;
#pragma unroll
  for (int off = 32; off; off >>= 1) {
    sum += __shfl_xor(sum, off);
    ssq += __shfl_xor(ssq, off);
  }
  float mean = sum * 0.0078125f;
  float var = ssq * 0.0078125f - mean * mean;
  float rs = rsqrtf(var + 1e-5f);
  float y0 = (x0 - mean) * rs * g[lane] + bta[lane];
  float y1 = (x1 - mean) * rs * g[lane + 64] + bta[lane + 64];
  size_t o = (size_t)tok * 128;
  hbf[o + lane] = f2bf(y0); hbf[o + lane + 64] = f2bf(y1);
}

// ---------------------------------------------------------------------------
// Fused QKV + flash attention.  One block (512 thr = 8 waves) per (b, head).
// Phase 1 (per wave, tokens wv*64..+63), PER-TF to cap register pressure:
//   load 4 token frags -> Q mfma -> pack -> qb; K mfma -> pack -> Ks LDS;
//   V mfma (per hf) -> pair-pack -> Vt LDS.  Frag-linear LDS (lane*16B).
// Phase 2: flash loop, P register-resident via packfrag, O^T=mfma(Vt,P^T).
// LDS 64KB -> 2 blocks/CU -> 4 waves/EU; regalloc pinned to that occupancy.
// ---------------------------------------------------------------------------
__global__ __launch_bounds__(512)
__attribute__((amdgpu_waves_per_eu(4, 4))) void attn_fused(
    const unsigned short* __restrict__ h, const unsigned short* __restrict__ Wa,
    const float* __restrict__ ab, unsigned short* __restrict__ obf) {
  __shared__ __bf16 Ks[32 * 512];   // 32 key-frags (16 keys x 32 d)
  __shared__ __bf16 Vt[32 * 512];   // [hf*16 + keyblock32] frags (16 d x 32 k)

  const int hh = blockIdx.x & 3, bl = blockIdx.x >> 2;
  const int t = threadIdx.x;
  const int lane = t & 63, wv = t >> 6;
  const int c = lane & 15, g = lane >> 4;
  const size_t tok0 = (size_t)bl * 512;
  const size_t myq = tok0 + wv * 64;

  const unsigned short* Wb = Wa + hh * 3 * 4096;
  const float* bq = ab + hh * 32;
  const float* bk = ab + 128 + hh * 32;
  const float* bv = ab + 256 + hh * 32;

  bf16x8 qb[4];
  f32x4 dv[2][2];                 // [tf&1][hf], live across a tf pair
#pragma unroll
  for (int tf = 0; tf < 4; ++tf) {
    bf16x8 a4[4];
#pragma unroll
    for (int kk = 0; kk < 4; ++kk)
      a4[kk] =
          *(const bf16x8*)(h + (myq + tf * 16 + c) * 128 + kk * 32 + g * 8);
    // ---- Q ----
    {
      f32x4 d0 = {}, d1 = {};
#pragma unroll
      for (int kk = 0; kk < 4; ++kk) {
        d0 = MFMA(*(const bf16x8*)(Wb + kk * 512 + lane * 8), a4[kk], d0,
                  0, 0, 0);
        d1 = MFMA(*(const bf16x8*)(Wb + (4 + kk) * 512 + lane * 8), a4[kk],
                  d1, 0, 0, 0);
      }
      float4 b0 = *(const float4*)(bq + g * 4);
      float4 b1 = *(const float4*)(bq + 16 + g * 4);
      d0[0] += b0.x; d0[1] += b0.y; d0[2] += b0.z; d0[3] += b0.w;
      d1[0] += b1.x; d1[1] += b1.y; d1[2] += b1.z; d1[3] += b1.w;
      qb[tf] = packfrag(d0, d1);
    }
    // ---- K ----
    {
      f32x4 d0 = {}, d1 = {};
#pragma unroll
      for (int kk = 0; kk < 4; ++kk) {
        d0 = MFMA(*(const bf16x8*)(Wb + 4096 + kk * 512 + lane * 8), a4[kk],
                  d0, 0, 0, 0);
        d1 = MFMA(*(const bf16x8*)(Wb + 4096 + (4 + kk) * 512 + lane * 8),
                  a4[kk], d1, 0, 0, 0);
      }
      float4 b0 = *(const float4*)(bk + g * 4);
      float4 b1 = *(const float4*)(bk + 16 + g * 4);
      d0[0] += b0.x; d0[1] += b0.y; d0[2] += b0.z; d0[3] += b0.w;
      d1[0] += b1.x; d1[1] += b1.y; d1[2] += b1.z; d1[3] += b1.w;
      *(bf16x8*)&Ks[(wv * 4 + tf) * 512 + lane * 8] = packfrag(d0, d1);
    }
    // ---- V ----
#pragma unroll
    for (int hf = 0; hf < 2; ++hf) {
      f32x4 tv = {};
#pragma unroll
      for (int kk = 0; kk < 4; ++kk)
        tv = MFMA(a4[kk],
                  *(const bf16x8*)(Wb + 8192 + (hf * 4 + kk) * 512 + lane * 8),
                  tv, 0, 0, 0);
      float bvv = bv[hf * 16 + c];
      tv[0] += bvv; tv[1] += bvv; tv[2] += bvv; tv[3] += bvv;
      dv[tf & 1][hf] = tv;
    }
    if (tf & 1) {
#pragma unroll
      for (int hf = 0; hf < 2; ++hf)
        *(bf16x8*)&Vt[(hf * 16 + wv * 2 + (tf >> 1)) * 512 + lane * 8] =
            packfrag(dv[0][hf], dv[1][hf]);
    }
  }
  __syncthreads();

  // ---- phase 2: flash attention over 8 key tiles of 64 ----
  f32x4 ot[4][2] = {};
  float l[4] = {0.f, 0.f, 0.f, 0.f};
  const f32x4 zz = {0.f, 0.f, 0.f, 0.f};

  for (int kt = 0; kt < 8; ++kt) {
    bf16x8 ka[4];
#pragma unroll
    for (int kf = 0; kf < 4; ++kf)
      ka[kf] = *(const bf16x8*)&Ks[(kt * 4 + kf) * 512 + lane * 8];
    bf16x8 vb2[2][2];
#pragma unroll
    for (int hf = 0; hf < 2; ++hf)
#pragma unroll
      for (int ksl = 0; ksl < 2; ++ksl)
        vb2[hf][ksl] =
            *(const bf16x8*)&Vt[(hf * 16 + kt * 2 + ksl) * 512 + lane * 8];

#pragma unroll
    for (int qf = 0; qf < 4; ++qf) {
      f32x4 sA = MFMA(ka[0], qb[qf], zz, 0, 0, 0);
      f32x4 sB = MFMA(ka[1], qb[qf], zz, 0, 0, 0);
      f32x4 sC = MFMA(ka[2], qb[qf], zz, 0, 0, 0);
      f32x4 sD = MFMA(ka[3], qb[qf], zz, 0, 0, 0);

      {
        float pa0 = EXP2(sA[0]), pa1 = EXP2(sA[1]);
        float pa2 = EXP2(sA[2]), pa3 = EXP2(sA[3]);
        float pb0 = EXP2(sB[0]), pb1 = EXP2(sB[1]);
        float pb2 = EXP2(sB[2]), pb3 = EXP2(sB[3]);
        l[qf] += ((pa0 + pa1) + (pa2 + pa3)) + ((pb0 + pb1) + (pb2 + pb3));
        f32x4 pa = {pa0, pa1, pa2, pa3};
        f32x4 pb = {pb0, pb1, pb2, pb3};
        bf16x8 pk = packfrag(pa, pb);
        ot[qf][0] = MFMA(vb2[0][0], pk, ot[qf][0], 0, 0, 0);
        ot[qf][1] = MFMA(vb2[1][0], pk, ot[qf][1], 0, 0, 0);
      }
      {
        float pa0 = EXP2(sC[0]), pa1 = EXP2(sC[1]);
        float pa2 = EXP2(sC[2]), pa3 = EXP2(sC[3]);
        float pb0 = EXP2(sD[0]), pb1 = EXP2(sD[1]);
        float pb2 = EXP2(sD[2]), pb3 = EXP2(sD[3]);
        l[qf] += ((pa0 + pa1) + (pa2 + pa3)) + ((pb0 + pb1) + (pb2 + pb3));
        f32x4 pa = {pa0, pa1, pa2, pa3};
        f32x4 pb = {pb0, pb1, pb2, pb3};
        bf16x8 pk = packfrag(pa, pb);
        ot[qf][0] = MFMA(vb2[0][1], pk, ot[qf][0], 0, 0, 0);
        ot[qf][1] = MFMA(vb2[1][1], pk, ot[qf][1], 0, 0, 0);
      }
    }
  }

#pragma unroll
  for (int qf = 0; qf < 4; ++qf) {
    l[qf] += __shfl_xor(l[qf], 16);
    l[qf] += __shfl_xor(l[qf], 32);
  }
#pragma unroll
  for (int qf = 0; qf < 4; ++qf) {
    float rl = 1.0f / l[qf];
#pragma unroll
    for (int hf = 0; hf < 2; ++hf) {
      ushort4 pk;
      pk.x = f2bf(ot[qf][hf][0] * rl);
      pk.y = f2bf(ot[qf][hf][1] * rl);
      pk.z = f2bf(ot[qf][hf][2] * rl);
      pk.w = f2bf(ot[qf][hf][3] * rl);
      *(ushort4*)(obf + (myq + qf * 16 + c) * 128 + hh * 32 + hf * 16 +
                  g * 4) = pk;
    }
  }
}

// ---------------------------------------------------------------------------
// Fused out-proj + residual + LayerNorm, register-transposed, no LDS/barrier.
// ---------------------------------------------------------------------------
__global__ __launch_bounds__(256) void oproj_ln(
    const unsigned short* __restrict__ A, const unsigned short* __restrict__ Wp,
    const float* __restrict__ bias, unsigned short* __restrict__ h,
    const float* __restrict__ gamma, const float* __restrict__ beta) {
  const int lane = threadIdx.x & 63, w = threadIdx.x >> 6;
  const int c = lane & 15, g = lane >> 4;
  const size_t tok0 = (size_t)blockIdx.x * 128 + w * 32;

  bf16x8 at[2][4];
#pragma unroll
  for (int tf = 0; tf < 2; ++tf)
#pragma unroll
    for (int kk = 0; kk < 4; ++kk)
      at[tf][kk] =
          *(const bf16x8*)(A + (tok0 + tf * 16 + c) * 128 + kk * 32 + g * 8);

  f32x4 acc[8][2] = {};
#pragma unroll
  for (int db = 0; db < 8; ++db)
#pragma unroll
    for (int kk = 0; kk < 4; ++kk) {
      bf16x8 wf = *(const bf16x8*)(Wp + (db * 4 + kk) * 512 + lane * 8);
      acc[db][0] = MFMA(wf, at[0][kk], acc[db][0], 0, 0, 0);
      acc[db][1] = MFMA(wf, at[1][kk], acc[db][1], 0, 0, 0);
    }

#pragma unroll
  for (int tf = 0; tf < 2; ++tf) {
    unsigned short* hrow = h + (tok0 + tf * 16 + c) * 128;
    float x[8][4];
    float s_ = 0.f, q_ = 0.f;
#pragma unroll
    for (int db = 0; db < 8; ++db) {
      float4 bvv = *(const float4*)(bias + db * 16 + g * 4);
      ushort4 rv = *(const ushort4*)(hrow + db * 16 + g * 4);
      x[db][0] = acc[db][tf][0] + bvv.x + bf2f(rv.x);
      x[db][1] = acc[db][tf][1] + bvv.y + bf2f(rv.y);
      x[db][2] = acc[db][tf][2] + bvv.z + bf2f(rv.z);
      x[db][3] = acc[db][tf][3] + bvv.w + bf2f(rv.w);
#pragma unroll
      for (int r = 0; r < 4; ++r) { s_ += x[db][r]; q_ += x[db][r] * x[db][r]; }
    }
    s_ += __shfl_xor(s_, 16); s_ += __shfl_xor(s_, 32);
    q_ += __shfl_xor(q_, 16); q_ += __shfl_xor(q_, 32);
    float mean = s_ * 0.0078125f;
    float var = q_ * 0.0078125f - mean * mean;
    float rs = rsqrtf(var + 1e-5f);
#pragma unroll
    for (int db = 0; db < 8; ++db) {
      float4 gv = *(const float4*)(gamma + db * 16 + g * 4);
      float4 bb = *(const float4*)(beta + db * 16 + g * 4);
      ushort4 o;
      o.x = f2bf((x[db][0] - mean) * rs * gv.x + bb.x);
      o.y = f2bf((x[db][1] - mean) * rs * gv.y + bb.y);
      o.z = f2bf((x[db][2] - mean) * rs * gv.z + bb.z);
      o.w = f2bf((x[db][3] - mean) * rs * gv.w + bb.w);
      *(ushort4*)(hrow + db * 16 + g * 4) = o;
    }
  }
}

// ---------------------------------------------------------------------------
// Fused FFN, register-transposed, G never leaves registers, no LDS/barriers.
// ---------------------------------------------------------------------------
__global__ __launch_bounds__(256) void ffn_reg(
    unsigned short* __restrict__ h, const unsigned short* __restrict__ W1p,
    const float* __restrict__ b1, const unsigned short* __restrict__ W2p,
    const float* __restrict__ b2, const float* __restrict__ gamma,
    const float* __restrict__ beta) {
  const int lane = threadIdx.x & 63, w = threadIdx.x >> 6;
  const int c = lane & 15, g = lane >> 4;
  const size_t tok0 = (size_t)blockIdx.x * 128 + w * 32;

  bf16x8 at[2][4];
#pragma unroll
  for (int tf = 0; tf < 2; ++tf)
#pragma unroll
    for (int kk = 0; kk < 4; ++kk)
      at[tf][kk] =
          *(const bf16x8*)(h + (tok0 + tf * 16 + c) * 128 + kk * 32 + g * 8);

  f32x4 acc[8][2] = {};
  for (int s = 0; s < 16; ++s) {          // 16 slices of 32 ff
    f32x4 d1[2][2] = {};                  // [ffhalf][tf]
#pragma unroll
    for (int kk = 0; kk < 4; ++kk) {
      bf16x8 wa = *(const bf16x8*)(W1p + ((2 * s) * 4 + kk) * 512 + lane * 8);
      bf16x8 wb = *(const bf16x8*)(W1p + ((2 * s + 1) * 4 + kk) * 512 + lane * 8);
      d1[0][0] = MFMA(wa, at[0][kk], d1[0][0], 0, 0, 0);
      d1[0][1] = MFMA(wa, at[1][kk], d1[0][1], 0, 0, 0);
      d1[1][0] = MFMA(wb, at[0][kk], d1[1][0], 0, 0, 0);
      d1[1][1] = MFMA(wb, at[1][kk], d1[1][1], 0, 0, 0);
    }
    float4 bva = *(const float4*)(b1 + s * 32 + g * 4);
    float4 bvb = *(const float4*)(b1 + s * 32 + 16 + g * 4);
    bf16x8 gp[2];
#pragma unroll
    for (int tf = 0; tf < 2; ++tf) {
      f32x4 pa, pb;
      pa[0] = fmaxf(d1[0][tf][0] + bva.x, 0.f);
      pa[1] = fmaxf(d1[0][tf][1] + bva.y, 0.f);
      pa[2] = fmaxf(d1[0][tf][2] + bva.z, 0.f);
      pa[3] = fmaxf(d1[0][tf][3] + bva.w, 0.f);
      pb[0] = fmaxf(d1[1][tf][0] + bvb.x, 0.f);
      pb[1] = fmaxf(d1[1][tf][1] + bvb.y, 0.f);
      pb[2] = fmaxf(d1[1][tf][2] + bvb.z, 0.f);
      pb[3] = fmaxf(d1[1][tf][3] + bvb.w, 0.f);
      gp[tf] = packfrag(pa, pb);
    }
#pragma unroll
    for (int db = 0; db < 8; ++db) {
      bf16x8 w2 = *(const bf16x8*)(W2p + (db * 16 + s) * 512 + lane * 8);
      acc[db][0] = MFMA(w2, gp[0], acc[db][0], 0, 0, 0);
      acc[db][1] = MFMA(w2, gp[1], acc[db][1], 0, 0, 0);
    }
  }

#pragma unroll
  for (int tf = 0; tf < 2; ++tf) {
    unsigned short* hrow = h + (tok0 + tf * 16 + c) * 128;
    float x[8][4];
    float s_ = 0.f, q_ = 0.f;
#pragma unroll
    for (int db = 0; db < 8; ++db) {
      float4 bvv = *(const float4*)(b2 + db * 16 + g * 4);
      ushort4 rv = *(const ushort4*)(hrow + db * 16 + g * 4);
      x[db][0] = acc[db][tf][0] + bvv.x + bf2f(rv.x);
      x[db][1] = acc[db][tf][1] + bvv.y + bf2f(rv.y);
      x[db][2] = acc[db][tf][2] + bvv.z + bf2f(rv.z);
      x[db][3] = acc[db][tf][3] + bvv.w + bf2f(rv.w);
#pragma unroll
      for (int r = 0; r < 4; ++r) { s_ += x[db][r]; q_ += x[db][r] * x[db][r]; }
    }
    s_ += __shfl_xor(s_, 16); s_ += __shfl_xor(s_, 32);
    q_ += __shfl_xor(q_, 16); q_ += __shfl_xor(q_, 32);
    float mean = s_ * 0.0078125f;
    float var = q_ * 0.0078125f - mean * mean;
    float rs = rsqrtf(var + 1e-5f);
#pragma unroll
    for (int db = 0; db < 8; ++db) {
      float4 gv = *(const float4*)(gamma + db * 16 + g * 4);
      float4 bb = *(const float4*)(beta + db * 16 + g * 4);
      ushort4 o;
      o.x = f2bf((x[db][0] - mean) * rs * gv.x + bb.x);
      o.y = f2bf((x[db][1] - mean) * rs * gv.y + bb.y);
      o.z = f2bf((x[db][2] - mean) * rs * gv.z + bb.z);
      o.w = f2bf((x[db][3] - mean) * rs * gv.w + bb.w);
      *(ushort4*)(hrow + db * 16 + g * 4) = o;
    }
  }
}

// ---------------------------------------------------------------------------
// Fused vocab projection + entropy, register-transposed, no LDS/barriers.
// ---------------------------------------------------------------------------
__global__ __launch_bounds__(256) void vocab_entropy(
    const unsigned short* __restrict__ h, const unsigned short* __restrict__ Wp,
    const float* __restrict__ bias, float* __restrict__ ent) {
  const int lane = threadIdx.x & 63, w = threadIdx.x >> 6;
  const int c = lane & 15, g = lane >> 4;
  const size_t tok0 = (size_t)blockIdx.x * 128 + w * 32;

  bf16x8 at[2][4];
#pragma unroll
  for (int tf = 0; tf < 2; ++tf)
#pragma unroll
    for (int kk = 0; kk < 4; ++kk)
      at[tf][kk] =
          *(const bf16x8*)(h + (tok0 + tf * 16 + c) * 128 + kk * 32 + g * 8);

  f32x4 acc[16][2] = {};
#pragma unroll
  for (int vb = 0; vb < 16; ++vb)
#pragma unroll
    for (int kk = 0; kk < 4; ++kk) {
      bf16x8 wf = *(const bf16x8*)(Wp + (vb * 4 + kk) * 512 + lane * 8);
      acc[vb][0] = MFMA(wf, at[0][kk], acc[vb][0], 0, 0, 0);
      acc[vb][1] = MFMA(wf, at[1][kk], acc[vb][1], 0, 0, 0);
    }

  const float L2E = 1.4426950408889634f;
#pragma unroll
  for (int tf = 0; tf < 2; ++tf) {
    float m_ = -1e30f;
#pragma unroll
    for (int vb = 0; vb < 16; ++vb) {
      float4 bvv = *(const float4*)(bias + vb * 16 + g * 4);
      acc[vb][tf][0] += bvv.x; acc[vb][tf][1] += bvv.y;
      acc[vb][tf][2] += bvv.z; acc[vb][tf][3] += bvv.w;
      m_ = fmaxf(m_, fmaxf(fmaxf(acc[vb][tf][0], acc[vb][tf][1]),
                           fmaxf(acc[vb][tf][2], acc[vb][tf][3])));
    }
    m_ = fmaxf(m_, __shfl_xor(m_, 16));
    m_ = fmaxf(m_, __shfl_xor(m_, 32));
    float z_ = 0.f, sx_ = 0.f;
#pragma unroll
    for (int vb = 0; vb < 16; ++vb)
#pragma unroll
      for (int r = 0; r < 4; ++r) {
        float xx = acc[vb][tf][r];
        float e = EXP2((xx - m_) * L2E);
        z_ += e; sx_ += e * xx;
      }
    z_ += __shfl_xor(z_, 16);  z_ += __shfl_xor(z_, 32);
    sx_ += __shfl_xor(sx_, 16); sx_ += __shfl_xor(sx_, 32);
    if (g == 0) ent[tok0 + tf * 16 + c] = m_ + logf(z_) - sx_ / z_;
  }
}

// ---------------------------------------------------------------------------
__global__ __launch_bounds__(64) void avg_entropy_kernel(
    const float* __restrict__ ent, float* __restrict__ out) {
  int s = blockIdx.x, lane = threadIdx.x;
  float a = 0.f;
  for (int b = lane; b < 256; b += 64) a += ent[(size_t)b * 512 + s];
#pragma unroll
  for (int off = 32; off; off >>= 1) a += __shfl_xor(a, off);
  if (lane == 0) out[s] = a * 0.00390625f;
}

__global__ __launch_bounds__(512) void seg_kernel(float* out) {
  __shared__ int cs[512];
  int i = threadIdx.x;
  float e = out[i];
  cs[i] = (i >= 1 && e > 4.0f) ? 1 : 0;
  __syncthreads();
  for (int off = 1; off < 512; off <<= 1) {
    int v = (i >= off) ? cs[i - off] : 0;
    __syncthreads();
    cs[i] += v;
    __syncthreads();
  }
  out[512 + i] = (float)cs[i];
}

// ---------------------------------------------------------------------------
extern "C" void kernel_launch(void* const* d_in, const int* in_sizes, int n_in,
                              void* d_out, int out_size, void* d_ws,
                              size_t ws_size, hipStream_t stream) {
  (void)in_sizes; (void)n_in; (void)out_size; (void)ws_size;
  const int*   input_bytes = (const int*)d_in[0];
  const float* emb    = (const float*)d_in[1];
  const float* pos    = (const float*)d_in[2];
  const float* ln_g   = (const float*)d_in[3];
  const float* ln_b   = (const float*)d_in[4];
  const float* attn_w = (const float*)d_in[5];
  const float* attn_b = (const float*)d_in[6];
  const float* out_w  = (const float*)d_in[7];
  const float* out_b  = (const float*)d_in[8];
  const float* ff1_w  = (const float*)d_in[9];
  const float* ff1_b  = (const float*)d_in[10];
  const float* ff2_w  = (const float*)d_in[11];
  const float* ff2_b  = (const float*)d_in[12];
  const float* n1_g   = (const float*)d_in[13];
  const float* n1_b   = (const float*)d_in[14];
  const float* n2_g   = (const float*)d_in[15];
  const float* n2_b   = (const float*)d_in[16];
  const float* proj_w = (const float*)d_in[17];
  const float* proj_b = (const float*)d_in[18];

  char* ws = (char*)d_ws;
  unsigned short* hbf  = (unsigned short*)(ws);                // 32 MB
  unsigned short* obf  = (unsigned short*)(ws + 33554432);     // 32 MB
  unsigned short* wbf  = (unsigned short*)(ws + 67108864);     // ~0.85 MB
  float*          absb = (float*)(ws + 68157440);              // 3 KB
  float*          entb = (float*)(ws + 68161536);              // 0.5 MB

  unsigned short* attnA = wbf;
  unsigned short* outwA = wbf + 98304;
  unsigned short* w1A   = wbf + 131072;
  unsigned short* w2A   = wbf + 262144;
  unsigned short* projA = wbf + 393216;

  conv_attn_headA<<<384, 256, 0, stream>>>(attn_w, attnA);
  conv_attn_b<<<3, 256, 0, stream>>>(attn_b, absb);
  for (int l = 0; l < 2; ++l) {
    conv_permA<<<64, 256, 0, stream>>>(out_w + l * 16384, outwA + l * 16384,
                                       128, 16384);
    conv_permA<<<256, 256, 0, stream>>>(ff1_w + l * 65536, w1A + l * 65536,
                                        128, 65536);
    conv_permA<<<256, 256, 0, stream>>>(ff2_w + l * 65536, w2A + l * 65536,
                                        512, 65536);
  }
  conv_permA<<<128, 256, 0, stream>>>(proj_w, projA, 128, 32768);

  embed_ln<<<32768, 256, 0, stream>>>(input_bytes, emb, pos, ln_g, ln_b, hbf);

  for (int l = 0; l < 2; ++l) {
    attn_fused<<<1024, 512, 0, stream>>>(hbf, attnA + l * 49152,
                                         absb + l * 384, obf);
    oproj_ln<<<1024, 256, 0, stream>>>(obf, outwA + l * 16384, out_b + l * 128,
                                       hbf, n1_g + l * 128, n1_b + l * 128);
    ffn_reg<<<1024, 256, 0, stream>>>(hbf, w1A + l * 65536, ff1_b + l * 512,
                                      w2A + l * 65536, ff2_b + l * 128,
                                      n2_g + l * 128, n2_b + l * 128);
  }

  vocab_entropy<<<1024, 256, 0, stream>>>(hbf, projA, proj_b, entb);
  avg_entropy_kernel<<<512, 64, 0, stream>>>(entb, (float*)d_out);
  seg_kernel<<<1, 512, 0, stream>>>((float*)d_out);
}